// Round 1
// baseline (3013.642 us; speedup 1.0000x reference)
//
#include <hip/hip_runtime.h>
#include <hip/hip_bf16.h>

#define B_ 64
#define N_ 245
#define NT_ 49
#define H_ 12
#define HD_ 64
#define C_ 768
#define C3_ 2304
#define M_ (B_*N_)         // 15680 tokens
#define SCALE_ 0.125f      // 64^-0.5
#define RPE_MAX_ 1792      // actual rpe_m = 1698

// ---------------- fp32 tiled GEMM: Co = A @ W^T + bias ----------------
// A: (M,K) row-major, W: (Nn,K) row-major, Co: (M,Nn). M%64==0, Nn%64==0, K%16==0.
__global__ __launch_bounds__(256) void gemm_bias_kernel(
    const float* __restrict__ A, const float* __restrict__ W,
    const float* __restrict__ bias, float* __restrict__ Co,
    int M, int Nn, int K)
{
  __shared__ __align__(16) float As[16][64];
  __shared__ __align__(16) float Ws[16][64];
  const int bn = blockIdx.x, bm = blockIdx.y;
  const int tid = threadIdx.x;
  const int tr = (tid >> 4) << 2;   // 0..60 (row group)
  const int tc = (tid & 15) << 2;   // 0..60 (col group)
  const int lr = tid >> 2;          // 0..63 loader row
  const int lk = (tid & 3) << 2;    // 0,4,8,12 loader k
  float acc[4][4] = {};
  const float* Arow = A + (size_t)(bm*64 + lr)*K + lk;
  const float* Wrow = W + (size_t)(bn*64 + lr)*K + lk;
  for (int k0 = 0; k0 < K; k0 += 16) {
    float4 a4 = *(const float4*)(Arow + k0);
    float4 w4 = *(const float4*)(Wrow + k0);
    As[lk+0][lr] = a4.x; As[lk+1][lr] = a4.y; As[lk+2][lr] = a4.z; As[lk+3][lr] = a4.w;
    Ws[lk+0][lr] = w4.x; Ws[lk+1][lr] = w4.y; Ws[lk+2][lr] = w4.z; Ws[lk+3][lr] = w4.w;
    __syncthreads();
    #pragma unroll
    for (int kk = 0; kk < 16; ++kk) {
      float4 av = *(const float4*)(&As[kk][tr]);
      float4 wv = *(const float4*)(&Ws[kk][tc]);
      float ar[4] = {av.x, av.y, av.z, av.w};
      float wr[4] = {wv.x, wv.y, wv.z, wv.w};
      #pragma unroll
      for (int ii = 0; ii < 4; ++ii)
        #pragma unroll
        for (int jj = 0; jj < 4; ++jj)
          acc[ii][jj] = fmaf(ar[ii], wr[jj], acc[ii][jj]);
    }
    __syncthreads();
  }
  #pragma unroll
  for (int ii = 0; ii < 4; ++ii) {
    #pragma unroll
    for (int jj = 0; jj < 4; ++jj) {
      int n = bn*64 + tc + jj;
      Co[(size_t)(bm*64 + tr + ii)*Nn + n] = acc[ii][jj] + bias[n];
    }
  }
}

// -------- template attention: out_t[b,h,i<49,d] = softmax_t(QK^T+rpe) @ boxmask --------
// one block per (b,h); 4 waves each own rows round-robin.
__global__ __launch_bounds__(256) void attn_template_kernel(
    const float* __restrict__ qkv, const float* __restrict__ boxmask,
    const float* __restrict__ rpe_table, const int* __restrict__ rpe_index,
    float* __restrict__ out_t, int rpe_m)
{
  __shared__ float q_s[NT_*64];
  __shared__ float k_s[64*NT_];    // transposed [d][j]
  __shared__ float bm_s[NT_*64];   // [j][d]
  __shared__ float rpe_s[RPE_MAX_];
  const int b = blockIdx.x / H_, h = blockIdx.x % H_;
  const int tid = threadIdx.x, lane = tid & 63, wid = tid >> 6;
  for (int idx = tid; idx < NT_*64; idx += 256) {
    int n = idx >> 6, d = idx & 63;
    size_t base = ((size_t)(b*N_ + n))*C3_ + h*64 + d;
    q_s[idx] = qkv[base];
    k_s[d*NT_ + n] = qkv[base + 768];
    bm_s[idx] = boxmask[((size_t)(b*NT_ + n))*C_ + h*64 + d];
  }
  for (int idx = tid; idx < rpe_m; idx += 256) rpe_s[idx] = rpe_table[h*rpe_m + idx];
  __syncthreads();
  for (int i = wid; i < NT_; i += 4) {
    float L = -1e30f;
    if (lane < NT_) {
      float s = 0.f;
      #pragma unroll
      for (int d = 0; d < 64; ++d) s = fmaf(q_s[i*64+d], k_s[d*NT_ + lane], s);
      L = s * SCALE_ + rpe_s[rpe_index[i*N_ + lane]];
    }
    float mx = L;
    #pragma unroll
    for (int off = 32; off; off >>= 1) mx = fmaxf(mx, __shfl_xor(mx, off));
    mx = fmaxf(mx, 0.f);                       // the 196 masked zeros join the max
    float e = (lane < NT_) ? __expf(L - mx) : 0.f;
    float S = e;
    #pragma unroll
    for (int off = 32; off; off >>= 1) S += __shfl_xor(S, off);
    float denom = S + 196.f * __expf(-mx);     // exp(0-mx) for each of N-NT masked cols
    float p = e / denom;
    float acc = 0.f;
    #pragma unroll
    for (int j = 0; j < NT_; ++j) {
      float pj = __shfl(p, j);
      acc = fmaf(pj, bm_s[j*64 + lane], acc);
    }
    out_t[(((size_t)(b*H_ + h))*NT_ + i)*64 + lane] = acc;
  }
}

// -------- factor[b,h,i] = t_vec[b,i,:] . box_w[h,:] + box_b[h]; one wave per task --------
__global__ __launch_bounds__(256) void factor_kernel(
    const float* __restrict__ out_t, const float* __restrict__ box_w,
    const float* __restrict__ box_b, float* __restrict__ factor)
{
  const int task = blockIdx.x * 4 + (threadIdx.x >> 6);
  const int lane = threadIdx.x & 63;
  if (task >= B_*H_*NT_) return;
  const int b = task / (H_*NT_);
  const int rem = task % (H_*NT_);
  const int h = rem / NT_, i = rem % NT_;
  float s = 0.f;
  #pragma unroll
  for (int t = 0; t < H_; ++t)  // t_vec[b,i,t*64+lane] = out_t[b,t,i,lane]
    s = fmaf(out_t[(((size_t)(b*H_ + t))*NT_ + i)*64 + lane],
             box_w[h*C_ + t*64 + lane], s);
  #pragma unroll
  for (int off = 32; off; off >>= 1) s += __shfl_xor(s, off);
  if (lane == 0) factor[task] = s + box_b[h];
}

// -------- full attention: logits (+rpe, ts-block *factor) -> softmax -> @V --------
__global__ __launch_bounds__(256) void attn_full_kernel(
    const float* __restrict__ qkv, const float* __restrict__ rpe_table,
    const int* __restrict__ rpe_index, const float* __restrict__ factor,
    float* __restrict__ attnout, int rpe_m)
{
  __shared__ float k_s[64*N_ + 16];  // transposed [d][j], small tail pad for r=3 overread
  __shared__ float v_s[N_*64];       // [j][d]
  __shared__ float rpe_s[RPE_MAX_];
  const int b = blockIdx.x / H_, h = blockIdx.x % H_;
  const int tid = threadIdx.x, lane = tid & 63, wid = tid >> 6;
  for (int idx = tid; idx < N_*64; idx += 256) {
    int n = idx >> 6, d = idx & 63;
    size_t base = ((size_t)(b*N_ + n))*C3_ + h*64 + d;
    k_s[d*N_ + n] = qkv[base + 768];
    v_s[idx]     = qkv[base + 1536];
  }
  for (int idx = tid; idx < rpe_m; idx += 256) rpe_s[idx] = rpe_table[h*rpe_m + idx];
  __syncthreads();
  for (int i = wid; i < N_; i += 4) {
    float qreg = qkv[((size_t)(b*N_ + i))*C3_ + h*64 + lane];
    float s0 = 0.f, s1 = 0.f, s2 = 0.f, s3 = 0.f;
    #pragma unroll
    for (int d = 0; d < 64; ++d) {
      float qd = __shfl(qreg, d);
      const float* kr = &k_s[d*N_];
      s0 = fmaf(qd, kr[lane      ], s0);
      s1 = fmaf(qd, kr[lane +  64], s1);
      s2 = fmaf(qd, kr[lane + 128], s2);
      s3 = fmaf(qd, kr[lane + 192], s3);   // lanes >=53 read pad/garbage; masked below
    }
    const int irow = i * N_;
    float f = 1.f;
    if (i < NT_) f = factor[(b*H_ + h)*NT_ + i];
    float L0 = s0 * SCALE_ + rpe_s[rpe_index[irow + lane]];
    float L1 = s1 * SCALE_ + rpe_s[rpe_index[irow + lane + 64]];
    float L2 = s2 * SCALE_ + rpe_s[rpe_index[irow + lane + 128]];
    if (i < NT_) {                     // template row: scale search-col logits by factor
      if (lane >= NT_) L0 *= f;
      L1 *= f; L2 *= f;
    }
    float L3 = -1e30f;
    const int j3 = 192 + lane;
    if (j3 < N_) {
      L3 = s3 * SCALE_ + rpe_s[rpe_index[irow + j3]];
      if (i < NT_) L3 *= f;
    }
    float mx = fmaxf(fmaxf(L0, L1), fmaxf(L2, L3));
    #pragma unroll
    for (int off = 32; off; off >>= 1) mx = fmaxf(mx, __shfl_xor(mx, off));
    float e0 = __expf(L0 - mx), e1 = __expf(L1 - mx);
    float e2 = __expf(L2 - mx), e3 = __expf(L3 - mx);   // L3=-1e30 -> 0
    float S = e0 + e1 + e2 + e3;
    #pragma unroll
    for (int off = 32; off; off >>= 1) S += __shfl_xor(S, off);
    const float inv = 1.f / S;
    const float p0 = e0*inv, p1 = e1*inv, p2 = e2*inv, p3 = e3*inv;
    float acc = 0.f;
    #pragma unroll
    for (int jj = 0; jj < 64; ++jj) acc = fmaf(__shfl(p0, jj), v_s[jj*64        + lane], acc);
    #pragma unroll
    for (int jj = 0; jj < 64; ++jj) acc = fmaf(__shfl(p1, jj), v_s[(64+jj)*64   + lane], acc);
    #pragma unroll
    for (int jj = 0; jj < 64; ++jj) acc = fmaf(__shfl(p2, jj), v_s[(128+jj)*64  + lane], acc);
    #pragma unroll
    for (int jj = 0; jj < 53; ++jj) acc = fmaf(__shfl(p3, jj), v_s[(192+jj)*64  + lane], acc);
    attnout[((size_t)(b*N_ + i))*C_ + h*64 + lane] = acc;
  }
}

extern "C" void kernel_launch(void* const* d_in, const int* in_sizes, int n_in,
                              void* d_out, int out_size, void* d_ws, size_t ws_size,
                              hipStream_t stream)
{
  const float* x         = (const float*)d_in[0];
  const float* boxmask   = (const float*)d_in[1];
  const float* qkv_w     = (const float*)d_in[2];
  const float* qkv_b     = (const float*)d_in[3];
  const float* proj_w    = (const float*)d_in[4];
  const float* proj_b    = (const float*)d_in[5];
  const float* box_w     = (const float*)d_in[6];
  const float* box_b     = (const float*)d_in[7];
  const float* rpe_table = (const float*)d_in[8];
  const int*   rpe_index = (const int*)d_in[9];
  const int rpe_m = in_sizes[8] / H_;   // 1698

  float* ws      = (float*)d_ws;
  float* qkv     = ws;                                   // M_*C3_   = 36,126,720 f
  float* out_t   = qkv   + (size_t)M_*C3_;               // B*H*49*64 = 2,408,448 f
  float* factor  = out_t + (size_t)B_*H_*NT_*HD_;        // 37,632 f
  float* attnout = factor + (size_t)B_*H_*NT_;           // M_*C_ = 12,042,240 f
  float* out     = (float*)d_out;

  // 1) QKV projection: (15680 x 768) @ (2304 x 768)^T
  gemm_bias_kernel<<<dim3(C3_/64, M_/64), 256, 0, stream>>>(x, qkv_w, qkv_b, qkv, M_, C3_, C_);
  // 2) template-block attention -> out_t
  attn_template_kernel<<<B_*H_, 256, 0, stream>>>(qkv, boxmask, rpe_table, rpe_index, out_t, rpe_m);
  // 3) factor GEMV
  factor_kernel<<<(B_*H_*NT_)/4, 256, 0, stream>>>(out_t, box_w, box_b, factor);
  // 4) full attention -> attnout
  attn_full_kernel<<<B_*H_, 256, 0, stream>>>(qkv, rpe_table, rpe_index, factor, attnout, rpe_m);
  // 5) output projection: (15680 x 768) @ (768 x 768)^T
  gemm_bias_kernel<<<dim3(C_/64, M_/64), 256, 0, stream>>>(attnout, proj_w, proj_b, out, M_, C_, C_);
}

// Round 2
// 1273.760 us; speedup vs baseline: 2.3659x; 2.3659x over previous
//
#include <hip/hip_runtime.h>
#include <hip/hip_bf16.h>

#define B_ 64
#define N_ 245
#define NT_ 49
#define H_ 12
#define HD_ 64
#define C_ 768
#define C3_ 2304
#define M_ (B_*N_)         // 15680 tokens
#define SCALE_ 0.125f      // 64^-0.5
#define RPE_MAX_ 1792      // actual rpe_m = 1698
#define NPAD_ 256

typedef short short8 __attribute__((ext_vector_type(8)));
typedef float f32x4 __attribute__((ext_vector_type(4)));

__device__ __forceinline__ ushort f2bf(float f) {   // fp32 -> bf16 RTN
  unsigned u = __builtin_bit_cast(unsigned, f);
  u += 0x7fffu + ((u >> 16) & 1u);
  return (ushort)(u >> 16);
}

// ---------------- fp32 tiled GEMM: Co = A @ W^T + bias ----------------
__global__ __launch_bounds__(256) void gemm_bias_kernel(
    const float* __restrict__ A, const float* __restrict__ W,
    const float* __restrict__ bias, float* __restrict__ Co,
    int M, int Nn, int K)
{
  __shared__ __align__(16) float As[16][64];
  __shared__ __align__(16) float Ws[16][64];
  const int bn = blockIdx.x, bm = blockIdx.y;
  const int tid = threadIdx.x;
  const int tr = (tid >> 4) << 2;
  const int tc = (tid & 15) << 2;
  const int lr = tid >> 2;
  const int lk = (tid & 3) << 2;
  float acc[4][4] = {};
  const float* Arow = A + (size_t)(bm*64 + lr)*K + lk;
  const float* Wrow = W + (size_t)(bn*64 + lr)*K + lk;
  for (int k0 = 0; k0 < K; k0 += 16) {
    float4 a4 = *(const float4*)(Arow + k0);
    float4 w4 = *(const float4*)(Wrow + k0);
    As[lk+0][lr] = a4.x; As[lk+1][lr] = a4.y; As[lk+2][lr] = a4.z; As[lk+3][lr] = a4.w;
    Ws[lk+0][lr] = w4.x; Ws[lk+1][lr] = w4.y; Ws[lk+2][lr] = w4.z; Ws[lk+3][lr] = w4.w;
    __syncthreads();
    #pragma unroll
    for (int kk = 0; kk < 16; ++kk) {
      float4 av = *(const float4*)(&As[kk][tr]);
      float4 wv = *(const float4*)(&Ws[kk][tc]);
      float ar[4] = {av.x, av.y, av.z, av.w};
      float wr[4] = {wv.x, wv.y, wv.z, wv.w};
      #pragma unroll
      for (int ii = 0; ii < 4; ++ii)
        #pragma unroll
        for (int jj = 0; jj < 4; ++jj)
          acc[ii][jj] = fmaf(ar[ii], wr[jj], acc[ii][jj]);
    }
    __syncthreads();
  }
  #pragma unroll
  for (int ii = 0; ii < 4; ++ii) {
    #pragma unroll
    for (int jj = 0; jj < 4; ++jj) {
      int n = bn*64 + tc + jj;
      Co[(size_t)(bm*64 + tr + ii)*Nn + n] = acc[ii][jj] + bias[n];
    }
  }
}

// -------- template attention (unchanged, fp32) --------
__global__ __launch_bounds__(256) void attn_template_kernel(
    const float* __restrict__ qkv, const float* __restrict__ boxmask,
    const float* __restrict__ rpe_table, const int* __restrict__ rpe_index,
    float* __restrict__ out_t, int rpe_m)
{
  __shared__ float q_s[NT_*64];
  __shared__ float k_s[64*NT_];
  __shared__ float bm_s[NT_*64];
  __shared__ float rpe_s[RPE_MAX_];
  const int b = blockIdx.x / H_, h = blockIdx.x % H_;
  const int tid = threadIdx.x, lane = tid & 63, wid = tid >> 6;
  for (int idx = tid; idx < NT_*64; idx += 256) {
    int n = idx >> 6, d = idx & 63;
    size_t base = ((size_t)(b*N_ + n))*C3_ + h*64 + d;
    q_s[idx] = qkv[base];
    k_s[d*NT_ + n] = qkv[base + 768];
    bm_s[idx] = boxmask[((size_t)(b*NT_ + n))*C_ + h*64 + d];
  }
  for (int idx = tid; idx < rpe_m; idx += 256) rpe_s[idx] = rpe_table[h*rpe_m + idx];
  __syncthreads();
  for (int i = wid; i < NT_; i += 4) {
    float L = -1e30f;
    if (lane < NT_) {
      float s = 0.f;
      #pragma unroll
      for (int d = 0; d < 64; ++d) s = fmaf(q_s[i*64+d], k_s[d*NT_ + lane], s);
      L = s * SCALE_ + rpe_s[rpe_index[i*N_ + lane]];
    }
    float mx = L;
    #pragma unroll
    for (int off = 32; off; off >>= 1) mx = fmaxf(mx, __shfl_xor(mx, off));
    mx = fmaxf(mx, 0.f);
    float e = (lane < NT_) ? __expf(L - mx) : 0.f;
    float S = e;
    #pragma unroll
    for (int off = 32; off; off >>= 1) S += __shfl_xor(S, off);
    float denom = S + 196.f * __expf(-mx);
    float p = e / denom;
    float acc = 0.f;
    #pragma unroll
    for (int j = 0; j < NT_; ++j) {
      float pj = __shfl(p, j);
      acc = fmaf(pj, bm_s[j*64 + lane], acc);
    }
    out_t[(((size_t)(b*H_ + h))*NT_ + i)*64 + lane] = acc;
  }
}

// -------- factor GEMV (unchanged) --------
__global__ __launch_bounds__(256) void factor_kernel(
    const float* __restrict__ out_t, const float* __restrict__ box_w,
    const float* __restrict__ box_b, float* __restrict__ factor)
{
  const int task = blockIdx.x * 4 + (threadIdx.x >> 6);
  const int lane = threadIdx.x & 63;
  if (task >= B_*H_*NT_) return;
  const int b = task / (H_*NT_);
  const int rem = task % (H_*NT_);
  const int h = rem / NT_, i = rem % NT_;
  float s = 0.f;
  #pragma unroll
  for (int t = 0; t < H_; ++t)
    s = fmaf(out_t[(((size_t)(b*H_ + t))*NT_ + i)*64 + lane],
             box_w[h*C_ + t*64 + lane], s);
  #pragma unroll
  for (int off = 32; off; off >>= 1) s += __shfl_xor(s, off);
  if (lane == 0) factor[task] = s + box_b[h];
}

// -------- dense transposed RPE bias: biasT[h][j][i] = rpe_table[h][rpe_index[i][j]] --------
__global__ __launch_bounds__(256) void bias_kernel(
    const float* __restrict__ rpe_table, const int* __restrict__ rpe_index,
    float* __restrict__ biasT, int rpe_m)
{
  int idx = blockIdx.x * 256 + threadIdx.x;
  if (idx >= H_*N_*N_) return;
  int h = idx / (N_*N_);
  int rem = idx % (N_*N_);
  int j = rem / N_;
  int i = rem % N_;   // i fastest -> coalesced biasT writes
  biasT[((size_t)h*NPAD_ + j)*NPAD_ + i] = rpe_table[h*rpe_m + rpe_index[i*N_ + j]];
}

// -------- MFMA flash attention: S^T = mfma(K, Q^T); softmax per-lane; O^T = mfma(V^T, P^T) --------
// grid: (b*H + h)*4 + rowblock; 256 threads = 4 waves, wave owns 16 q-rows.
__global__ __launch_bounds__(256) void attn_mfma_kernel(
    const float* __restrict__ qkv, const float* __restrict__ biasT,
    const float* __restrict__ factor, float* __restrict__ attnout)
{
  __shared__ __align__(16) ushort kp_lds[NPAD_*64];   // K[j][d] swz bf16; then P[i][j] swz
  __shared__ __align__(16) ushort vt_lds[64*NPAD_];   // V^T[d][j] swz bf16
  const int bx = blockIdx.x;
  const int bh = bx >> 2, rb = bx & 3;
  const int b = bh / H_, h = bh % H_;
  const int tid = threadIdx.x, lane = tid & 63, wid = tid >> 6;
  const int g = lane >> 4, li = lane & 15;

  // ---- stage K and V^T as bf16, XOR-swizzled (G4: rows stride 128B/512B are 16-way else) ----
  for (int t = tid; t < NPAD_*16; t += 256) {
    int j = t >> 4, d = (t & 15) * 4;
    float4 kv = make_float4(0.f,0.f,0.f,0.f), vv = make_float4(0.f,0.f,0.f,0.f);
    if (j < N_) {
      size_t base = ((size_t)(b*N_ + j))*C3_ + h*64 + d;
      kv = *(const float4*)(qkv + base + 768);
      vv = *(const float4*)(qkv + base + 1536);
    }
    unsigned lo = (unsigned)f2bf(kv.x) | ((unsigned)f2bf(kv.y) << 16);
    unsigned hi = (unsigned)f2bf(kv.z) | ((unsigned)f2bf(kv.w) << 16);
    *(uint2*)(kp_lds + j*64 + (d ^ ((j&7)<<3))) = make_uint2(lo, hi);
    ushort vb0 = f2bf(vv.x), vb1 = f2bf(vv.y), vb2 = f2bf(vv.z), vb3 = f2bf(vv.w);
    vt_lds[(d+0)*NPAD_ + (j ^ (((d+0)&7)<<3))] = vb0;
    vt_lds[(d+1)*NPAD_ + (j ^ (((d+1)&7)<<3))] = vb1;
    vt_lds[(d+2)*NPAD_ + (j ^ (((d+2)&7)<<3))] = vb2;
    vt_lds[(d+3)*NPAD_ + (j ^ (((d+3)&7)<<3))] = vb3;
  }
  __syncthreads();

  // ---- Q B-fragments straight from global (col = li, k = kc*32 + g*8 + b) ----
  const int i0 = rb*64 + wid*16;
  const int ig = i0 + li;
  const int iq = (ig < N_) ? ig : (N_-1);
  short8 bq[2];
  {
    const float* qp = qkv + ((size_t)(b*N_ + iq))*C3_ + h*64;
    #pragma unroll
    for (int kc = 0; kc < 2; ++kc) {
      int d0 = kc*32 + g*8;
      float4 qa = *(const float4*)(qp + d0);
      float4 qb = *(const float4*)(qp + d0 + 4);
      short8 f;
      f[0]=(short)f2bf(qa.x); f[1]=(short)f2bf(qa.y); f[2]=(short)f2bf(qa.z); f[3]=(short)f2bf(qa.w);
      f[4]=(short)f2bf(qb.x); f[5]=(short)f2bf(qb.y); f[6]=(short)f2bf(qb.z); f[7]=(short)f2bf(qb.w);
      bq[kc] = f;
    }
  }

  // ---- QK^T: S^T frags, j = jt*16 + g*4 + r, i = i0 + li ----
  f32x4 sacc[16];
  #pragma unroll
  for (int jt = 0; jt < 16; ++jt) sacc[jt] = (f32x4){0.f,0.f,0.f,0.f};
  #pragma unroll
  for (int jt = 0; jt < 16; ++jt) {
    int jr = jt*16 + li;
    #pragma unroll
    for (int kc = 0; kc < 2; ++kc) {
      short8 af = *(const short8*)(kp_lds + jr*64 + ((kc*32 + g*8) ^ ((jr&7)<<3)));
      sacc[jt] = __builtin_amdgcn_mfma_f32_16x16x32_bf16(af, bq[kc], sacc[jt], 0, 0, 0);
    }
  }
  __syncthreads();   // all waves done reading K; kp_lds becomes P

  // ---- bias + factor + masked softmax (row i lives in lanes {li, li+16, li+32, li+48}) ----
  float fac = 1.0f;
  if (ig < NT_) fac = factor[bh*NT_ + ig];
  const float* bT = biasT + (size_t)h*NPAD_*NPAD_;
  float mloc = -1e30f;
  #pragma unroll
  for (int jt = 0; jt < 16; ++jt) {
    #pragma unroll
    for (int r = 0; r < 4; ++r) {
      int j = jt*16 + g*4 + r;
      float sv = sacc[jt][r] * SCALE_ + bT[(size_t)j*NPAD_ + i0 + li];
      if (ig < NT_ && j >= NT_) sv *= fac;     // template-row -> search-col rescale
      if (j >= N_) sv = -1e30f;                // padded keys
      sacc[jt][r] = sv;
      mloc = fmaxf(mloc, sv);
    }
  }
  mloc = fmaxf(mloc, __shfl_xor(mloc, 16));
  mloc = fmaxf(mloc, __shfl_xor(mloc, 32));
  float ssum = 0.f;
  #pragma unroll
  for (int jt = 0; jt < 16; ++jt) {
    #pragma unroll
    for (int r = 0; r < 4; ++r) {
      float e = __expf(sacc[jt][r] - mloc);
      sacc[jt][r] = e;
      ssum += e;
    }
  }
  ssum += __shfl_xor(ssum, 16);
  ssum += __shfl_xor(ssum, 32);
  const float inv = 1.0f / ssum;

  // ---- pack P to bf16, write swizzled P[i=li][j] into this wave's 8KB of kp_lds ----
  ushort* pbase = kp_lds + wid*4096 + li*256;
  const int swz = (li & 7) << 3;
  #pragma unroll
  for (int jt = 0; jt < 16; ++jt) {
    unsigned w0 = (unsigned)f2bf(sacc[jt][0]*inv) | ((unsigned)f2bf(sacc[jt][1]*inv) << 16);
    unsigned w1 = (unsigned)f2bf(sacc[jt][2]*inv) | ((unsigned)f2bf(sacc[jt][3]*inv) << 16);
    *(uint2*)(pbase + ((jt*16 + g*4) ^ swz)) = make_uint2(w0, w1);
  }

  // ---- PV: O^T[d][i] = mfma(V^T, P^T) ----
  f32x4 oacc[4];
  #pragma unroll
  for (int dt = 0; dt < 4; ++dt) oacc[dt] = (f32x4){0.f,0.f,0.f,0.f};
  #pragma unroll
  for (int jc = 0; jc < 8; ++jc) {
    short8 pf = *(const short8*)(pbase + ((jc*32 + g*8) ^ swz));
    #pragma unroll
    for (int dt = 0; dt < 4; ++dt) {
      int row = dt*16 + li;
      short8 vf = *(const short8*)(vt_lds + row*NPAD_ + ((jc*32 + g*8) ^ ((row&7)<<3)));
      oacc[dt] = __builtin_amdgcn_mfma_f32_16x16x32_bf16(vf, pf, oacc[dt], 0, 0, 0);
    }
  }

  // ---- store: lane holds col i = ig, rows d = dt*16 + g*4 + r ----
  if (ig < N_) {
    float* op = attnout + ((size_t)(b*N_ + ig))*C_ + h*64;
    #pragma unroll
    for (int dt = 0; dt < 4; ++dt) {
      #pragma unroll
      for (int r = 0; r < 4; ++r)
        op[dt*16 + g*4 + r] = oacc[dt][r];
    }
  }
}

extern "C" void kernel_launch(void* const* d_in, const int* in_sizes, int n_in,
                              void* d_out, int out_size, void* d_ws, size_t ws_size,
                              hipStream_t stream)
{
  const float* x         = (const float*)d_in[0];
  const float* boxmask   = (const float*)d_in[1];
  const float* qkv_w     = (const float*)d_in[2];
  const float* qkv_b     = (const float*)d_in[3];
  const float* proj_w    = (const float*)d_in[4];
  const float* proj_b    = (const float*)d_in[5];
  const float* box_w     = (const float*)d_in[6];
  const float* box_b     = (const float*)d_in[7];
  const float* rpe_table = (const float*)d_in[8];
  const int*   rpe_index = (const int*)d_in[9];
  const int rpe_m = in_sizes[8] / H_;   // 1698

  float* ws      = (float*)d_ws;
  float* qkv     = ws;                                   // 36,126,720 f
  float* out_t   = qkv     + (size_t)M_*C3_;             // 2,408,448 f
  float* factor  = out_t   + (size_t)B_*H_*NT_*HD_;      // 37,632 f
  float* attnout = factor  + (size_t)B_*H_*NT_;          // 12,042,240 f
  float* biasT   = attnout + (size_t)M_*C_;              // 786,432 f (12*256*256)
  float* out     = (float*)d_out;

  // 0) dense transposed RPE bias (independent of x)
  bias_kernel<<<(H_*N_*N_ + 255)/256, 256, 0, stream>>>(rpe_table, rpe_index, biasT, rpe_m);
  // 1) QKV projection
  gemm_bias_kernel<<<dim3(C3_/64, M_/64), 256, 0, stream>>>(x, qkv_w, qkv_b, qkv, M_, C3_, C_);
  // 2) template-block attention -> out_t
  attn_template_kernel<<<B_*H_, 256, 0, stream>>>(qkv, boxmask, rpe_table, rpe_index, out_t, rpe_m);
  // 3) factor GEMV
  factor_kernel<<<(B_*H_*NT_)/4, 256, 0, stream>>>(out_t, box_w, box_b, factor);
  // 4) MFMA attention -> attnout
  attn_mfma_kernel<<<B_*H_*4, 256, 0, stream>>>(qkv, biasT, factor, attnout);
  // 5) output projection
  gemm_bias_kernel<<<dim3(C_/64, M_/64), 256, 0, stream>>>(attnout, proj_w, proj_b, out, M_, C_, C_);
}

// Round 3
// 532.842 us; speedup vs baseline: 5.6558x; 2.3905x over previous
//
#include <hip/hip_runtime.h>
#include <hip/hip_bf16.h>

#define B_ 64
#define N_ 245
#define NT_ 49
#define H_ 12
#define HD_ 64
#define C_ 768
#define C3_ 2304
#define M_ (B_*N_)         // 15680 tokens
#define MP_ 15744          // padded to 123*128
#define MB_ 123
#define KB_ 24             // 768/32 k-blocks
#define SCALE_ 0.125f
#define RPE_MAX_ 1792
#define NPAD_ 256

typedef short short8 __attribute__((ext_vector_type(8)));
typedef float f32x4 __attribute__((ext_vector_type(4)));
typedef ushort us8 __attribute__((ext_vector_type(8)));
typedef ushort us4 __attribute__((ext_vector_type(4)));

__device__ __forceinline__ ushort f2bf(float f) {   // fp32 -> bf16 RTN
  unsigned u = __builtin_bit_cast(unsigned, f);
  u += 0x7fffu + ((u >> 16) & 1u);
  return (ushort)(u >> 16);
}

// split a = hi + lo (both bf16-truncated; dropped error ~2^-16 relative)
__device__ __forceinline__ void split2(float a, ushort& hi, ushort& lo) {
  unsigned u = __builtin_bit_cast(unsigned, a);
  hi = (ushort)(u >> 16);
  float hf = __builtin_bit_cast(float, u & 0xffff0000u);
  lo = (ushort)(__builtin_bit_cast(unsigned, a - hf) >> 16);
}

// ---- build pre-tiled pre-swizzled hi|lo image: [mb*KB+kb][row 128][hi 32 | lo 32] ----
// row layout: 8 chunks of 8 bf16 (chunks 0-3 hi, 4-7 lo), chunk pos XOR (row&7).
__global__ __launch_bounds__(256) void split_img_kernel(
    const float* __restrict__ A, ushort* __restrict__ img, int rows, int K, int total)
{
  int idx = blockIdx.x*256 + threadIdx.x;
  if (idx >= total) return;
  const int ch = idx & 3;
  const int r  = (idx >> 2) & 127;
  const int t  = idx >> 9;               // mb*KBl + kb
  const int KBl = K >> 5;
  const int kb = t % KBl, mb = t / KBl;
  const int m = mb*128 + r;
  float4 v0 = make_float4(0,0,0,0), v1 = make_float4(0,0,0,0);
  if (m < rows) {
    const float* p = A + (size_t)m*K + kb*32 + ch*8;
    v0 = *(const float4*)p; v1 = *(const float4*)(p+4);
  }
  float vals[8] = {v0.x,v0.y,v0.z,v0.w,v1.x,v1.y,v1.z,v1.w};
  us8 hv, lv;
  #pragma unroll
  for (int e = 0; e < 8; ++e) { ushort hh, ll; split2(vals[e], hh, ll); hv[e]=hh; lv[e]=ll; }
  ushort* base = img + ((size_t)t*128 + r)*64;
  const int sw = (ch ^ (r&7))*8;
  *(us8*)(base + sw)        = hv;
  *(us8*)(base + (sw ^ 32)) = lv;
}

// ---- async stage one 16KB tile (128 rows x 128B) linearly into LDS ----
__device__ __forceinline__ void stage_tile(const ushort* __restrict__ src, ushort* dst,
                                           int wid, int lane) {
  #pragma unroll
  for (int t = 0; t < 4; ++t) {
    const int o = (wid*4 + t) * 512;   // ushort units; 1KB per wave-instr
    __builtin_amdgcn_global_load_lds(
      (const __attribute__((address_space(1))) unsigned int*)(src + o + lane*8),
      (__attribute__((address_space(3))) unsigned int*)(dst + o),
      16, 0, 0);
  }
}

// ---- bf16x3 GEMM: Co = A @ B^T + bias, from pre-split images ----
// 128x128 tile, 4 waves (2x2 of 64x64), BK=32, double-buffered LDS.
__global__ __launch_bounds__(256) void gemm3_kernel(
    const ushort* __restrict__ Aimg, const ushort* __restrict__ Bimg,
    const float* __restrict__ bias, float* __restrict__ Co,
    int KB, int Nn, int M)
{
  __shared__ __align__(16) ushort lds[2][16384];   // [buf][A 8192 | B 8192]
  const int tid = threadIdx.x, lane = tid & 63, wid = tid >> 6;
  const int g = lane >> 4, li = lane & 15;
  const int nb = blockIdx.x, mb = blockIdx.y;
  const int wr = (wid >> 1) * 64, wc = (wid & 1) * 64;

  const ushort* Abase = Aimg + (size_t)mb * KB * 8192;
  const ushort* Bbase = Bimg + (size_t)nb * KB * 8192;

  f32x4 acc[4][4];
  #pragma unroll
  for (int i = 0; i < 4; ++i)
    #pragma unroll
    for (int j = 0; j < 4; ++j) acc[i][j] = (f32x4){0.f,0.f,0.f,0.f};

  stage_tile(Abase, &lds[0][0],    wid, lane);
  stage_tile(Bbase, &lds[0][8192], wid, lane);
  __syncthreads();

  for (int kb = 0; kb < KB; ++kb) {
    const int cur = kb & 1;
    if (kb + 1 < KB) {
      stage_tile(Abase + (size_t)(kb+1)*8192, &lds[cur^1][0],    wid, lane);
      stage_tile(Bbase + (size_t)(kb+1)*8192, &lds[cur^1][8192], wid, lane);
    }
    short8 ah[4], al[4], bh[4], bl[4];
    #pragma unroll
    for (int t = 0; t < 4; ++t) {
      const int ra = wr + t*16 + li;
      const ushort* Ar = &lds[cur][ra*64];
      const int ca = (g ^ (ra & 7)) * 8;
      ah[t] = *(const short8*)(Ar + ca);
      al[t] = *(const short8*)(Ar + (ca ^ 32));
      const int rb = wc + t*16 + li;
      const ushort* Br = &lds[cur][8192 + rb*64];
      const int cb = (g ^ (rb & 7)) * 8;
      bh[t] = *(const short8*)(Br + cb);
      bl[t] = *(const short8*)(Br + (cb ^ 32));
    }
    #pragma unroll
    for (int i = 0; i < 4; ++i)
      #pragma unroll
      for (int j = 0; j < 4; ++j) {
        acc[i][j] = __builtin_amdgcn_mfma_f32_16x16x32_bf16(ah[i], bh[j], acc[i][j], 0,0,0);
        acc[i][j] = __builtin_amdgcn_mfma_f32_16x16x32_bf16(al[i], bh[j], acc[i][j], 0,0,0);
        acc[i][j] = __builtin_amdgcn_mfma_f32_16x16x32_bf16(ah[i], bl[j], acc[i][j], 0,0,0);
      }
    __syncthreads();
  }

  #pragma unroll
  for (int i = 0; i < 4; ++i) {
    const int m0 = mb*128 + wr + i*16 + g*4;
    #pragma unroll
    for (int j = 0; j < 4; ++j) {
      const int n = nb*128 + wc + j*16 + li;
      const float bv = bias[n];
      #pragma unroll
      for (int rr = 0; rr < 4; ++rr) {
        const int m = m0 + rr;
        if (m < M) Co[(size_t)m * Nn + n] = acc[i][j][rr] + bv;
      }
    }
  }
}

// -------- template attention (fp32) --------
__global__ __launch_bounds__(256) void attn_template_kernel(
    const float* __restrict__ qkv, const float* __restrict__ boxmask,
    const float* __restrict__ rpe_table, const int* __restrict__ rpe_index,
    float* __restrict__ out_t, int rpe_m)
{
  __shared__ float q_s[NT_*64];
  __shared__ float k_s[64*NT_];
  __shared__ float bm_s[NT_*64];
  __shared__ float rpe_s[RPE_MAX_];
  const int b = blockIdx.x / H_, h = blockIdx.x % H_;
  const int tid = threadIdx.x, lane = tid & 63, wid = tid >> 6;
  for (int idx = tid; idx < NT_*64; idx += 256) {
    int n = idx >> 6, d = idx & 63;
    size_t base = ((size_t)(b*N_ + n))*C3_ + h*64 + d;
    q_s[idx] = qkv[base];
    k_s[d*NT_ + n] = qkv[base + 768];
    bm_s[idx] = boxmask[((size_t)(b*NT_ + n))*C_ + h*64 + d];
  }
  for (int idx = tid; idx < rpe_m; idx += 256) rpe_s[idx] = rpe_table[h*rpe_m + idx];
  __syncthreads();
  for (int i = wid; i < NT_; i += 4) {
    float L = -1e30f;
    if (lane < NT_) {
      float s = 0.f;
      #pragma unroll
      for (int d = 0; d < 64; ++d) s = fmaf(q_s[i*64+d], k_s[d*NT_ + lane], s);
      L = s * SCALE_ + rpe_s[rpe_index[i*N_ + lane]];
    }
    float mx = L;
    #pragma unroll
    for (int off = 32; off; off >>= 1) mx = fmaxf(mx, __shfl_xor(mx, off));
    mx = fmaxf(mx, 0.f);
    float e = (lane < NT_) ? __expf(L - mx) : 0.f;
    float S = e;
    #pragma unroll
    for (int off = 32; off; off >>= 1) S += __shfl_xor(S, off);
    float denom = S + 196.f * __expf(-mx);
    float p = e / denom;
    float acc = 0.f;
    #pragma unroll
    for (int j = 0; j < NT_; ++j) {
      float pj = __shfl(p, j);
      acc = fmaf(pj, bm_s[j*64 + lane], acc);
    }
    out_t[(((size_t)(b*H_ + h))*NT_ + i)*64 + lane] = acc;
  }
}

// -------- factor GEMV --------
__global__ __launch_bounds__(256) void factor_kernel(
    const float* __restrict__ out_t, const float* __restrict__ box_w,
    const float* __restrict__ box_b, float* __restrict__ factor)
{
  const int task = blockIdx.x * 4 + (threadIdx.x >> 6);
  const int lane = threadIdx.x & 63;
  if (task >= B_*H_*NT_) return;
  const int b = task / (H_*NT_);
  const int rem = task % (H_*NT_);
  const int h = rem / NT_, i = rem % NT_;
  float s = 0.f;
  #pragma unroll
  for (int t = 0; t < H_; ++t)
    s = fmaf(out_t[(((size_t)(b*H_ + t))*NT_ + i)*64 + lane],
             box_w[h*C_ + t*64 + lane], s);
  #pragma unroll
  for (int off = 32; off; off >>= 1) s += __shfl_xor(s, off);
  if (lane == 0) factor[task] = s + box_b[h];
}

// -------- dense transposed RPE bias --------
__global__ __launch_bounds__(256) void bias_kernel(
    const float* __restrict__ rpe_table, const int* __restrict__ rpe_index,
    float* __restrict__ biasT, int rpe_m)
{
  int idx = blockIdx.x * 256 + threadIdx.x;
  if (idx >= H_*N_*N_) return;
  int h = idx / (N_*N_);
  int rem = idx % (N_*N_);
  int j = rem / N_;
  int i = rem % N_;
  biasT[((size_t)h*NPAD_ + j)*NPAD_ + i] = rpe_table[h*rpe_m + rpe_index[i*N_ + j]];
}

// -------- MFMA flash attention; writes hi/lo image for the proj GEMM --------
__global__ __launch_bounds__(256) void attn_mfma_kernel(
    const float* __restrict__ qkv, const float* __restrict__ biasT,
    const float* __restrict__ factor, ushort* __restrict__ attnimg)
{
  __shared__ __align__(16) ushort kp_lds[NPAD_*64];
  __shared__ __align__(16) ushort vt_lds[64*NPAD_];
  const int bx = blockIdx.x;
  const int bh = bx >> 2, rb = bx & 3;
  const int b = bh / H_, h = bh % H_;
  const int tid = threadIdx.x, lane = tid & 63, wid = tid >> 6;
  const int g = lane >> 4, li = lane & 15;

  for (int t = tid; t < NPAD_*16; t += 256) {
    int j = t >> 4, d = (t & 15) * 4;
    float4 kv = make_float4(0.f,0.f,0.f,0.f), vv = make_float4(0.f,0.f,0.f,0.f);
    if (j < N_) {
      size_t base = ((size_t)(b*N_ + j))*C3_ + h*64 + d;
      kv = *(const float4*)(qkv + base + 768);
      vv = *(const float4*)(qkv + base + 1536);
    }
    unsigned lo = (unsigned)f2bf(kv.x) | ((unsigned)f2bf(kv.y) << 16);
    unsigned hi = (unsigned)f2bf(kv.z) | ((unsigned)f2bf(kv.w) << 16);
    *(uint2*)(kp_lds + j*64 + (d ^ ((j&7)<<3))) = make_uint2(lo, hi);
    vt_lds[(d+0)*NPAD_ + (j ^ (((d+0)&7)<<3))] = f2bf(vv.x);
    vt_lds[(d+1)*NPAD_ + (j ^ (((d+1)&7)<<3))] = f2bf(vv.y);
    vt_lds[(d+2)*NPAD_ + (j ^ (((d+2)&7)<<3))] = f2bf(vv.z);
    vt_lds[(d+3)*NPAD_ + (j ^ (((d+3)&7)<<3))] = f2bf(vv.w);
  }
  __syncthreads();

  const int i0 = rb*64 + wid*16;
  const int ig = i0 + li;
  const int iq = (ig < N_) ? ig : (N_-1);
  short8 bq[2];
  {
    const float* qp = qkv + ((size_t)(b*N_ + iq))*C3_ + h*64;
    #pragma unroll
    for (int kc = 0; kc < 2; ++kc) {
      int d0 = kc*32 + g*8;
      float4 qa = *(const float4*)(qp + d0);
      float4 qb = *(const float4*)(qp + d0 + 4);
      short8 f;
      f[0]=(short)f2bf(qa.x); f[1]=(short)f2bf(qa.y); f[2]=(short)f2bf(qa.z); f[3]=(short)f2bf(qa.w);
      f[4]=(short)f2bf(qb.x); f[5]=(short)f2bf(qb.y); f[6]=(short)f2bf(qb.z); f[7]=(short)f2bf(qb.w);
      bq[kc] = f;
    }
  }

  f32x4 sacc[16];
  #pragma unroll
  for (int jt = 0; jt < 16; ++jt) sacc[jt] = (f32x4){0.f,0.f,0.f,0.f};
  #pragma unroll
  for (int jt = 0; jt < 16; ++jt) {
    int jr = jt*16 + li;
    #pragma unroll
    for (int kc = 0; kc < 2; ++kc) {
      short8 af = *(const short8*)(kp_lds + jr*64 + ((kc*32 + g*8) ^ ((jr&7)<<3)));
      sacc[jt] = __builtin_amdgcn_mfma_f32_16x16x32_bf16(af, bq[kc], sacc[jt], 0, 0, 0);
    }
  }
  __syncthreads();

  float fac = 1.0f;
  if (ig < NT_) fac = factor[bh*NT_ + ig];
  const float* bT = biasT + (size_t)h*NPAD_*NPAD_;
  float mloc = -1e30f;
  #pragma unroll
  for (int jt = 0; jt < 16; ++jt) {
    #pragma unroll
    for (int r = 0; r < 4; ++r) {
      int j = jt*16 + g*4 + r;
      float sv = sacc[jt][r] * SCALE_ + bT[(size_t)j*NPAD_ + i0 + li];
      if (ig < NT_ && j >= NT_) sv *= fac;
      if (j >= N_) sv = -1e30f;
      sacc[jt][r] = sv;
      mloc = fmaxf(mloc, sv);
    }
  }
  mloc = fmaxf(mloc, __shfl_xor(mloc, 16));
  mloc = fmaxf(mloc, __shfl_xor(mloc, 32));
  float ssum = 0.f;
  #pragma unroll
  for (int jt = 0; jt < 16; ++jt) {
    #pragma unroll
    for (int r = 0; r < 4; ++r) {
      float e = __expf(sacc[jt][r] - mloc);
      sacc[jt][r] = e;
      ssum += e;
    }
  }
  ssum += __shfl_xor(ssum, 16);
  ssum += __shfl_xor(ssum, 32);
  const float inv = 1.0f / ssum;

  ushort* pbase = kp_lds + wid*4096 + li*256;
  const int swz = (li & 7) << 3;
  #pragma unroll
  for (int jt = 0; jt < 16; ++jt) {
    unsigned w0 = (unsigned)f2bf(sacc[jt][0]*inv) | ((unsigned)f2bf(sacc[jt][1]*inv) << 16);
    unsigned w1 = (unsigned)f2bf(sacc[jt][2]*inv) | ((unsigned)f2bf(sacc[jt][3]*inv) << 16);
    *(uint2*)(pbase + ((jt*16 + g*4) ^ swz)) = make_uint2(w0, w1);
  }

  f32x4 oacc[4];
  #pragma unroll
  for (int dt = 0; dt < 4; ++dt) oacc[dt] = (f32x4){0.f,0.f,0.f,0.f};
  #pragma unroll
  for (int jc = 0; jc < 8; ++jc) {
    short8 pf = *(const short8*)(pbase + ((jc*32 + g*8) ^ swz));
    #pragma unroll
    for (int dt = 0; dt < 4; ++dt) {
      int row = dt*16 + li;
      short8 vf = *(const short8*)(vt_lds + row*NPAD_ + ((jc*32 + g*8) ^ ((row&7)<<3)));
      oacc[dt] = __builtin_amdgcn_mfma_f32_16x16x32_bf16(vf, pf, oacc[dt], 0, 0, 0);
    }
  }

  // ---- write hi/lo swizzled image rows (token m = row, channel c = h*64+d = k) ----
  if (ig < N_) {
    const int m = b*N_ + ig;
    const int mbm = m >> 7, r = m & 127;
    const int rx = r & 7;
    #pragma unroll
    for (int dt = 0; dt < 4; ++dt) {
      const int kb = h*2 + (dt >> 1);
      const int kc = (dt & 1)*16 + g*4;
      const int ch = kc >> 3, wo = kc & 7;
      ushort* base = attnimg + (((size_t)(mbm*KB_ + kb))*128 + r)*64;
      us4 hv, lv;
      #pragma unroll
      for (int rr = 0; rr < 4; ++rr) {
        ushort hh, ll; split2(oacc[dt][rr], hh, ll);
        hv[rr] = hh; lv[rr] = ll;
      }
      *(us4*)(base + ((ch ^ rx)*8 + wo))       = hv;
      *(us4*)(base + (((ch ^ 4) ^ rx)*8 + wo)) = lv;
    }
  }
}

extern "C" void kernel_launch(void* const* d_in, const int* in_sizes, int n_in,
                              void* d_out, int out_size, void* d_ws, size_t ws_size,
                              hipStream_t stream)
{
  const float* x         = (const float*)d_in[0];
  const float* boxmask   = (const float*)d_in[1];
  const float* qkv_w     = (const float*)d_in[2];
  const float* qkv_b     = (const float*)d_in[3];
  const float* proj_w    = (const float*)d_in[4];
  const float* proj_b    = (const float*)d_in[5];
  const float* box_w     = (const float*)d_in[6];
  const float* box_b     = (const float*)d_in[7];
  const float* rpe_table = (const float*)d_in[8];
  const int*   rpe_index = (const int*)d_in[9];
  const int rpe_m = in_sizes[8] / H_;   // 1698

  float* ws      = (float*)d_ws;
  float* qkv     = ws;                                   // 36,126,720 f
  float* out_t   = qkv     + (size_t)M_*C3_;             // 2,408,448 f
  float* factor  = out_t   + (size_t)B_*H_*NT_*HD_;      // 37,632 f
  float* biasT   = factor  + (size_t)B_*H_*NT_;          // 786,432 f
  ushort* ximg   = (ushort*)(biasT + (size_t)H_*NPAD_*NPAD_); // 24,182,784 us (also attnimg)
  ushort* wqkvimg  = ximg + (size_t)MP_*C_*2;            // 3,538,944 us
  ushort* wprojimg = wqkvimg + (size_t)C3_*C_*2;         // 1,179,648 us
  ushort* attnimg  = ximg;   // alias: x image dead after QKV GEMM
  float* out     = (float*)d_out;

  // 0) RPE bias table + input splits
  bias_kernel<<<(H_*N_*N_ + 255)/256, 256, 0, stream>>>(rpe_table, rpe_index, biasT, rpe_m);
  split_img_kernel<<<(MB_*KB_*512 + 255)/256, 256, 0, stream>>>(x, ximg, M_, C_, MB_*KB_*512);
  split_img_kernel<<<(18*KB_*512 + 255)/256, 256, 0, stream>>>(qkv_w, wqkvimg, C3_, C_, 18*KB_*512);
  split_img_kernel<<<(6*KB_*512 + 255)/256, 256, 0, stream>>>(proj_w, wprojimg, C_, C_, 6*KB_*512);
  // 1) QKV projection (bf16x3 MFMA)
  gemm3_kernel<<<dim3(C3_/128, MB_), 256, 0, stream>>>(ximg, wqkvimg, qkv_b, qkv, KB_, C3_, M_);
  // 2) template-block attention -> out_t
  attn_template_kernel<<<B_*H_, 256, 0, stream>>>(qkv, boxmask, rpe_table, rpe_index, out_t, rpe_m);
  // 3) factor GEMV
  factor_kernel<<<(B_*H_*NT_)/4, 256, 0, stream>>>(out_t, box_w, box_b, factor);
  // 4) MFMA attention -> attn image (hi/lo, overwrites x image)
  attn_mfma_kernel<<<B_*H_*4, 256, 0, stream>>>(qkv, biasT, factor, attnimg);
  // 5) output projection (bf16x3 MFMA)
  gemm3_kernel<<<dim3(C_/128, MB_), 256, 0, stream>>>(attnimg, wprojimg, proj_b, out, KB_, C_, M_);
}

// Round 4
// 493.468 us; speedup vs baseline: 6.1071x; 1.0798x over previous
//
#include <hip/hip_runtime.h>
#include <hip/hip_bf16.h>

#define B_ 64
#define N_ 245
#define NT_ 49
#define H_ 12
#define HD_ 64
#define C_ 768
#define C3_ 2304
#define M_ (B_*N_)         // 15680 tokens
#define MP_ 15744          // padded to 123*128
#define MB_ 123
#define KB_ 24             // 768/32 k-blocks
#define SCALE_ 0.125f
#define RPE_MAX_ 1792
#define NPAD_ 256

typedef short short8 __attribute__((ext_vector_type(8)));
typedef float f32x4 __attribute__((ext_vector_type(4)));
typedef ushort us8 __attribute__((ext_vector_type(8)));
typedef ushort us4 __attribute__((ext_vector_type(4)));

__device__ __forceinline__ ushort f2bf(float f) {   // fp32 -> bf16 RTN
  unsigned u = __builtin_bit_cast(unsigned, f);
  u += 0x7fffu + ((u >> 16) & 1u);
  return (ushort)(u >> 16);
}
__device__ __forceinline__ float bf2f(ushort u) {
  return __builtin_bit_cast(float, ((unsigned)u) << 16);
}
// split a = hi + lo (both bf16; dropped error ~2^-16 relative)
__device__ __forceinline__ void split2(float a, ushort& hi, ushort& lo) {
  unsigned u = __builtin_bit_cast(unsigned, a);
  hi = (ushort)(u >> 16);
  float hf = __builtin_bit_cast(float, u & 0xffff0000u);
  lo = (ushort)(__builtin_bit_cast(unsigned, a - hf) >> 16);
}

// ---- pre-tiled pre-swizzled hi|lo image: [blk][row 128][hi 32 | lo 32] ----
__global__ __launch_bounds__(256) void split_img_kernel(
    const float* __restrict__ A, ushort* __restrict__ img, int rows, int K, int total)
{
  int idx = blockIdx.x*256 + threadIdx.x;
  if (idx >= total) return;
  const int ch = idx & 3;
  const int r  = (idx >> 2) & 127;
  const int t  = idx >> 9;
  const int KBl = K >> 5;
  const int kb = t % KBl, mb = t / KBl;
  const int m = mb*128 + r;
  float4 v0 = make_float4(0,0,0,0), v1 = make_float4(0,0,0,0);
  if (m < rows) {
    const float* p = A + (size_t)m*K + kb*32 + ch*8;
    v0 = *(const float4*)p; v1 = *(const float4*)(p+4);
  }
  float vals[8] = {v0.x,v0.y,v0.z,v0.w,v1.x,v1.y,v1.z,v1.w};
  us8 hv, lv;
  #pragma unroll
  for (int e = 0; e < 8; ++e) { ushort hh, ll; split2(vals[e], hh, ll); hv[e]=hh; lv[e]=ll; }
  ushort* base = img + ((size_t)t*128 + r)*64;
  const int sw = (ch ^ (r&7))*8;
  *(us8*)(base + sw)        = hv;
  *(us8*)(base + (sw ^ 32)) = lv;
}

// ---- stage one 16KB tile linearly into LDS ----
__device__ __forceinline__ void stage_tile(const ushort* __restrict__ src, ushort* dst,
                                           int wid, int lane) {
  #pragma unroll
  for (int t = 0; t < 4; ++t) {
    const int o = (wid*4 + t) * 512;
    __builtin_amdgcn_global_load_lds(
      (const __attribute__((address_space(1))) unsigned int*)(src + o + lane*8),
      (__attribute__((address_space(3))) unsigned int*)(dst + o),
      16, 0, 0);
  }
}

// ---- bf16x3 GEMM (token-major A): Co = A @ B^T + bias, fp32 out (proj) ----
__global__ __launch_bounds__(256) void gemm3_kernel(
    const ushort* __restrict__ Aimg, const ushort* __restrict__ Bimg,
    const float* __restrict__ bias, float* __restrict__ Co,
    int KB, int Nn, int M)
{
  __shared__ __align__(16) ushort lds[2][16384];
  const int tid = threadIdx.x, lane = tid & 63, wid = tid >> 6;
  const int g = lane >> 4, li = lane & 15;
  const int nb = blockIdx.x, mb = blockIdx.y;
  const int wr = (wid >> 1) * 64, wc = (wid & 1) * 64;

  const ushort* Abase = Aimg + (size_t)mb * KB * 8192;
  const ushort* Bbase = Bimg + (size_t)nb * KB * 8192;

  f32x4 acc[4][4];
  #pragma unroll
  for (int i = 0; i < 4; ++i)
    #pragma unroll
    for (int j = 0; j < 4; ++j) acc[i][j] = (f32x4){0.f,0.f,0.f,0.f};

  stage_tile(Abase, &lds[0][0],    wid, lane);
  stage_tile(Bbase, &lds[0][8192], wid, lane);
  __syncthreads();

  for (int kb = 0; kb < KB; ++kb) {
    const int cur = kb & 1;
    if (kb + 1 < KB) {
      stage_tile(Abase + (size_t)(kb+1)*8192, &lds[cur^1][0],    wid, lane);
      stage_tile(Bbase + (size_t)(kb+1)*8192, &lds[cur^1][8192], wid, lane);
    }
    short8 ah[4], al[4], bh[4], bl[4];
    #pragma unroll
    for (int t = 0; t < 4; ++t) {
      const int ra = wr + t*16 + li;
      const ushort* Ar = &lds[cur][ra*64];
      const int ca = (g ^ (ra & 7)) * 8;
      ah[t] = *(const short8*)(Ar + ca);
      al[t] = *(const short8*)(Ar + (ca ^ 32));
      const int rb = wc + t*16 + li;
      const ushort* Br = &lds[cur][8192 + rb*64];
      const int cb = (g ^ (rb & 7)) * 8;
      bh[t] = *(const short8*)(Br + cb);
      bl[t] = *(const short8*)(Br + (cb ^ 32));
    }
    #pragma unroll
    for (int i = 0; i < 4; ++i)
      #pragma unroll
      for (int j = 0; j < 4; ++j) {
        acc[i][j] = __builtin_amdgcn_mfma_f32_16x16x32_bf16(ah[i], bh[j], acc[i][j], 0,0,0);
        acc[i][j] = __builtin_amdgcn_mfma_f32_16x16x32_bf16(al[i], bh[j], acc[i][j], 0,0,0);
        acc[i][j] = __builtin_amdgcn_mfma_f32_16x16x32_bf16(ah[i], bl[j], acc[i][j], 0,0,0);
      }
    __syncthreads();
  }

  #pragma unroll
  for (int i = 0; i < 4; ++i) {
    const int m0 = mb*128 + wr + i*16 + g*4;
    #pragma unroll
    for (int j = 0; j < 4; ++j) {
      const int n = nb*128 + wc + j*16 + li;
      const float bv = bias[n];
      #pragma unroll
      for (int rr = 0; rr < 4; ++rr) {
        const int m = m0 + rr;
        if (m < M) Co[(size_t)m * Nn + n] = acc[i][j][rr] + bv;
      }
    }
  }
}

// ---- bf16x3 QKV GEMM (W-major A): writes bf16 Q/K/VT images directly ----
// A = qkv_w image (2304 ch rows), B = x image (tokens). acc quad = 4 consecutive channels.
__global__ __launch_bounds__(256) void gemm3_qkv_kernel(
    const ushort* __restrict__ Aimg, const ushort* __restrict__ Bimg,
    const float* __restrict__ bias,
    ushort* __restrict__ Qimg, ushort* __restrict__ Kimg, ushort* __restrict__ VTimg,
    int KB)
{
  __shared__ __align__(16) ushort lds[2][16384];
  const int tid = threadIdx.x, lane = tid & 63, wid = tid >> 6;
  const int g = lane >> 4, li = lane & 15;
  const int nb = blockIdx.x, mb = blockIdx.y;    // nb: token block, mb: channel block
  const int wr = (wid >> 1) * 64, wc = (wid & 1) * 64;

  const ushort* Abase = Aimg + (size_t)mb * KB * 8192;
  const ushort* Bbase = Bimg + (size_t)nb * KB * 8192;

  f32x4 acc[4][4];
  #pragma unroll
  for (int i = 0; i < 4; ++i)
    #pragma unroll
    for (int j = 0; j < 4; ++j) acc[i][j] = (f32x4){0.f,0.f,0.f,0.f};

  stage_tile(Abase, &lds[0][0],    wid, lane);
  stage_tile(Bbase, &lds[0][8192], wid, lane);
  __syncthreads();

  for (int kb = 0; kb < KB; ++kb) {
    const int cur = kb & 1;
    if (kb + 1 < KB) {
      stage_tile(Abase + (size_t)(kb+1)*8192, &lds[cur^1][0],    wid, lane);
      stage_tile(Bbase + (size_t)(kb+1)*8192, &lds[cur^1][8192], wid, lane);
    }
    short8 ah[4], al[4], bh[4], bl[4];
    #pragma unroll
    for (int t = 0; t < 4; ++t) {
      const int ra = wr + t*16 + li;
      const ushort* Ar = &lds[cur][ra*64];
      const int ca = (g ^ (ra & 7)) * 8;
      ah[t] = *(const short8*)(Ar + ca);
      al[t] = *(const short8*)(Ar + (ca ^ 32));
      const int rb = wc + t*16 + li;
      const ushort* Br = &lds[cur][8192 + rb*64];
      const int cb = (g ^ (rb & 7)) * 8;
      bh[t] = *(const short8*)(Br + cb);
      bl[t] = *(const short8*)(Br + (cb ^ 32));
    }
    #pragma unroll
    for (int i = 0; i < 4; ++i)
      #pragma unroll
      for (int j = 0; j < 4; ++j) {
        acc[i][j] = __builtin_amdgcn_mfma_f32_16x16x32_bf16(ah[i], bh[j], acc[i][j], 0,0,0);
        acc[i][j] = __builtin_amdgcn_mfma_f32_16x16x32_bf16(al[i], bh[j], acc[i][j], 0,0,0);
        acc[i][j] = __builtin_amdgcn_mfma_f32_16x16x32_bf16(ah[i], bl[j], acc[i][j], 0,0,0);
      }
    __syncthreads();
  }

  // epilogue: quad = channels ch0..ch0+3 at one token per (j,li)
  #pragma unroll
  for (int i = 0; i < 4; ++i) {
    const int ch0 = mb*128 + wr + i*16 + g*4;
    const int part = ch0 / 768;           // 0=q 1=k 2=v (uniform within quad/tile)
    const int rem  = ch0 - part*768;
    const int h = rem >> 6, d0 = rem & 63;
    const float b0 = bias[ch0+0], b1 = bias[ch0+1], b2 = bias[ch0+2], b3 = bias[ch0+3];
    #pragma unroll
    for (int j = 0; j < 4; ++j) {
      const int tok = nb*128 + wc + j*16 + li;
      if (tok < M_) {
        const int b = tok / 245;
        const int jl = tok - b*245;
        const int bh = b*H_ + h;
        ushort e0, e1, e2, e3;
        e0 = f2bf(acc[i][j][0] + b0); e1 = f2bf(acc[i][j][1] + b1);
        e2 = f2bf(acc[i][j][2] + b2); e3 = f2bf(acc[i][j][3] + b3);
        if (part == 0) {
          us4 q4 = {e0,e1,e2,e3};
          *(us4*)(Qimg + ((size_t)bh*NPAD_ + jl)*64 + d0) = q4;
        } else if (part == 1) {
          us4 k4 = {e0,e1,e2,e3};
          *(us4*)(Kimg + ((size_t)bh*NPAD_ + jl)*64 + (d0 ^ ((jl&7)<<3))) = k4;
        } else {
          VTimg[((size_t)bh*64 + d0+0)*NPAD_ + (jl ^ (((d0+0)&7)<<3))] = e0;
          VTimg[((size_t)bh*64 + d0+1)*NPAD_ + (jl ^ (((d0+1)&7)<<3))] = e1;
          VTimg[((size_t)bh*64 + d0+2)*NPAD_ + (jl ^ (((d0+2)&7)<<3))] = e2;
          VTimg[((size_t)bh*64 + d0+3)*NPAD_ + (jl ^ (((d0+3)&7)<<3))] = e3;
        }
      }
    }
  }
}

// -------- template attention (bf16 Q/K images, fp32 math) --------
__global__ __launch_bounds__(256) void attn_template_kernel(
    const ushort* __restrict__ Qimg, const ushort* __restrict__ Kimg,
    const float* __restrict__ boxmask,
    const float* __restrict__ rpe_table, const int* __restrict__ rpe_index,
    float* __restrict__ out_t, int rpe_m)
{
  __shared__ float q_s[NT_*64];
  __shared__ float k_s[64*NT_];
  __shared__ float bm_s[NT_*64];
  __shared__ float rpe_s[RPE_MAX_];
  const int bh = blockIdx.x;
  const int b = bh / H_, h = bh % H_;
  const int tid = threadIdx.x, lane = tid & 63, wid = tid >> 6;
  for (int idx = tid; idx < NT_*64; idx += 256) {
    int n = idx >> 6, d = idx & 63;
    q_s[idx]       = bf2f(Qimg[((size_t)bh*NPAD_ + n)*64 + d]);
    k_s[d*NT_ + n] = bf2f(Kimg[((size_t)bh*NPAD_ + n)*64 + (d ^ ((n&7)<<3))]);
    bm_s[idx] = boxmask[((size_t)(b*NT_ + n))*C_ + h*64 + d];
  }
  for (int idx = tid; idx < rpe_m; idx += 256) rpe_s[idx] = rpe_table[h*rpe_m + idx];
  __syncthreads();
  for (int i = wid; i < NT_; i += 4) {
    float L = -1e30f;
    if (lane < NT_) {
      float s = 0.f;
      #pragma unroll
      for (int d = 0; d < 64; ++d) s = fmaf(q_s[i*64+d], k_s[d*NT_ + lane], s);
      L = s * SCALE_ + rpe_s[rpe_index[i*N_ + lane]];
    }
    float mx = L;
    #pragma unroll
    for (int off = 32; off; off >>= 1) mx = fmaxf(mx, __shfl_xor(mx, off));
    mx = fmaxf(mx, 0.f);
    float e = (lane < NT_) ? __expf(L - mx) : 0.f;
    float S = e;
    #pragma unroll
    for (int off = 32; off; off >>= 1) S += __shfl_xor(S, off);
    float denom = S + 196.f * __expf(-mx);
    float p = e / denom;
    float acc = 0.f;
    #pragma unroll
    for (int j = 0; j < NT_; ++j) {
      float pj = __shfl(p, j);
      acc = fmaf(pj, bm_s[j*64 + lane], acc);
    }
    out_t[(((size_t)bh)*NT_ + i)*64 + lane] = acc;
  }
}

// -------- factor GEMV --------
__global__ __launch_bounds__(256) void factor_kernel(
    const float* __restrict__ out_t, const float* __restrict__ box_w,
    const float* __restrict__ box_b, float* __restrict__ factor)
{
  const int task = blockIdx.x * 4 + (threadIdx.x >> 6);
  const int lane = threadIdx.x & 63;
  if (task >= B_*H_*NT_) return;
  const int b = task / (H_*NT_);
  const int rem = task % (H_*NT_);
  const int h = rem / NT_, i = rem % NT_;
  float s = 0.f;
  #pragma unroll
  for (int t = 0; t < H_; ++t)
    s = fmaf(out_t[(((size_t)(b*H_ + t))*NT_ + i)*64 + lane],
             box_w[h*C_ + t*64 + lane], s);
  #pragma unroll
  for (int off = 32; off; off >>= 1) s += __shfl_xor(s, off);
  if (lane == 0) factor[task] = s + box_b[h];
}

// -------- dense transposed RPE bias --------
__global__ __launch_bounds__(256) void bias_kernel(
    const float* __restrict__ rpe_table, const int* __restrict__ rpe_index,
    float* __restrict__ biasT, int rpe_m)
{
  int idx = blockIdx.x * 256 + threadIdx.x;
  if (idx >= H_*N_*N_) return;
  int h = idx / (N_*N_);
  int rem = idx % (N_*N_);
  int j = rem / N_;
  int i = rem % N_;
  biasT[((size_t)h*NPAD_ + j)*NPAD_ + i] = rpe_table[h*rpe_m + rpe_index[i*N_ + j]];
}

// -------- MFMA flash attention from bf16 images; writes hi/lo image for proj --------
__global__ __launch_bounds__(256) void attn_mfma_kernel(
    const ushort* __restrict__ Qimg, const ushort* __restrict__ Kimg,
    const ushort* __restrict__ VTimg, const float* __restrict__ biasT,
    const float* __restrict__ factor, ushort* __restrict__ attnimg)
{
  __shared__ __align__(16) ushort kp_lds[NPAD_*64];   // K image; later P
  __shared__ __align__(16) ushort vt_lds[64*NPAD_];   // V^T image
  const int bx = blockIdx.x;
  const int bh = bx >> 2, rb = bx & 3;
  const int b = bh / H_, h = bh % H_;
  const int tid = threadIdx.x, lane = tid & 63, wid = tid >> 6;
  const int g = lane >> 4, li = lane & 15;

  // ---- direct image -> LDS (linear dest, pre-swizzled source) ----
  const ushort* Kb = Kimg  + (size_t)bh*16384;
  const ushort* Vb = VTimg + (size_t)bh*16384;
  #pragma unroll
  for (int t = 0; t < 8; ++t) {
    const int o = (t*4 + wid) * 512;
    __builtin_amdgcn_global_load_lds(
      (const __attribute__((address_space(1))) unsigned int*)(Kb + o + lane*8),
      (__attribute__((address_space(3))) unsigned int*)(kp_lds + o), 16, 0, 0);
    __builtin_amdgcn_global_load_lds(
      (const __attribute__((address_space(1))) unsigned int*)(Vb + o + lane*8),
      (__attribute__((address_space(3))) unsigned int*)(vt_lds + o), 16, 0, 0);
  }

  const int i0 = rb*64 + wid*16;
  const int ig = i0 + li;
  const int iq = (ig < N_) ? ig : (N_-1);
  short8 bq[2];
  {
    const ushort* qp = Qimg + ((size_t)bh*NPAD_ + iq)*64;
    bq[0] = *(const short8*)(qp + g*8);
    bq[1] = *(const short8*)(qp + 32 + g*8);
  }
  __syncthreads();

  f32x4 sacc[16];
  #pragma unroll
  for (int jt = 0; jt < 16; ++jt) sacc[jt] = (f32x4){0.f,0.f,0.f,0.f};
  #pragma unroll
  for (int jt = 0; jt < 16; ++jt) {
    int jr = jt*16 + li;
    #pragma unroll
    for (int kc = 0; kc < 2; ++kc) {
      short8 af = *(const short8*)(kp_lds + jr*64 + ((kc*32 + g*8) ^ ((jr&7)<<3)));
      sacc[jt] = __builtin_amdgcn_mfma_f32_16x16x32_bf16(af, bq[kc], sacc[jt], 0, 0, 0);
    }
  }
  __syncthreads();

  float fac = 1.0f;
  if (ig < NT_) fac = factor[bh*NT_ + ig];
  const float* bT = biasT + (size_t)h*NPAD_*NPAD_;
  float mloc = -1e30f;
  #pragma unroll
  for (int jt = 0; jt < 16; ++jt) {
    #pragma unroll
    for (int r = 0; r < 4; ++r) {
      int j = jt*16 + g*4 + r;
      float sv = sacc[jt][r] * SCALE_ + bT[(size_t)j*NPAD_ + i0 + li];
      if (ig < NT_ && j >= NT_) sv *= fac;
      if (j >= N_) sv = -1e30f;
      sacc[jt][r] = sv;
      mloc = fmaxf(mloc, sv);
    }
  }
  mloc = fmaxf(mloc, __shfl_xor(mloc, 16));
  mloc = fmaxf(mloc, __shfl_xor(mloc, 32));
  float ssum = 0.f;
  #pragma unroll
  for (int jt = 0; jt < 16; ++jt) {
    #pragma unroll
    for (int r = 0; r < 4; ++r) {
      float e = __expf(sacc[jt][r] - mloc);
      sacc[jt][r] = e;
      ssum += e;
    }
  }
  ssum += __shfl_xor(ssum, 16);
  ssum += __shfl_xor(ssum, 32);
  const float inv = 1.0f / ssum;

  ushort* pbase = kp_lds + wid*4096 + li*256;
  const int swz = (li & 7) << 3;
  #pragma unroll
  for (int jt = 0; jt < 16; ++jt) {
    unsigned w0 = (unsigned)f2bf(sacc[jt][0]*inv) | ((unsigned)f2bf(sacc[jt][1]*inv) << 16);
    unsigned w1 = (unsigned)f2bf(sacc[jt][2]*inv) | ((unsigned)f2bf(sacc[jt][3]*inv) << 16);
    *(uint2*)(pbase + ((jt*16 + g*4) ^ swz)) = make_uint2(w0, w1);
  }

  f32x4 oacc[4];
  #pragma unroll
  for (int dt = 0; dt < 4; ++dt) oacc[dt] = (f32x4){0.f,0.f,0.f,0.f};
  #pragma unroll
  for (int jc = 0; jc < 8; ++jc) {
    short8 pf = *(const short8*)(pbase + ((jc*32 + g*8) ^ swz));
    #pragma unroll
    for (int dt = 0; dt < 4; ++dt) {
      int row = dt*16 + li;
      short8 vf = *(const short8*)(vt_lds + row*NPAD_ + ((jc*32 + g*8) ^ ((row&7)<<3)));
      oacc[dt] = __builtin_amdgcn_mfma_f32_16x16x32_bf16(vf, pf, oacc[dt], 0, 0, 0);
    }
  }

  if (ig < N_) {
    const int m = b*N_ + ig;
    const int mbm = m >> 7, r = m & 127;
    const int rx = r & 7;
    #pragma unroll
    for (int dt = 0; dt < 4; ++dt) {
      const int kb = h*2 + (dt >> 1);
      const int kc = (dt & 1)*16 + g*4;
      const int ch = kc >> 3, wo = kc & 7;
      ushort* base = attnimg + (((size_t)(mbm*KB_ + kb))*128 + r)*64;
      us4 hv, lv;
      #pragma unroll
      for (int rr = 0; rr < 4; ++rr) {
        ushort hh, ll; split2(oacc[dt][rr], hh, ll);
        hv[rr] = hh; lv[rr] = ll;
      }
      *(us4*)(base + ((ch ^ rx)*8 + wo))       = hv;
      *(us4*)(base + (((ch ^ 4) ^ rx)*8 + wo)) = lv;
    }
  }
}

extern "C" void kernel_launch(void* const* d_in, const int* in_sizes, int n_in,
                              void* d_out, int out_size, void* d_ws, size_t ws_size,
                              hipStream_t stream)
{
  const float* x         = (const float*)d_in[0];
  const float* boxmask   = (const float*)d_in[1];
  const float* qkv_w     = (const float*)d_in[2];
  const float* qkv_b     = (const float*)d_in[3];
  const float* proj_w    = (const float*)d_in[4];
  const float* proj_b    = (const float*)d_in[5];
  const float* box_w     = (const float*)d_in[6];
  const float* box_b     = (const float*)d_in[7];
  const float* rpe_table = (const float*)d_in[8];
  const int*   rpe_index = (const int*)d_in[9];
  const int rpe_m = in_sizes[8] / H_;   // 1698

  float* ws      = (float*)d_ws;
  float* out_t   = ws;                                   // 2,408,448 f
  float* factor  = out_t  + (size_t)B_*H_*NT_*HD_;       // 37,632 f
  float* biasT   = factor + (size_t)B_*H_*NT_;           // 786,432 f
  ushort* ximg    = (ushort*)(biasT + (size_t)H_*NPAD_*NPAD_);
  ushort* wqkvimg  = ximg     + (size_t)MP_*C_*2;        // 24,182,784 us
  ushort* wprojimg = wqkvimg  + (size_t)C3_*C_*2;        // 3,538,944 us
  ushort* Qimg     = wprojimg + (size_t)C_*C_*2;         // 1,179,648 us
  ushort* Kimg     = Qimg     + (size_t)B_*H_*NPAD_*64;  // 12,582,912 us each
  ushort* VTimg    = Kimg     + (size_t)B_*H_*NPAD_*64;
  ushort* attnimg  = ximg;   // alias: x image dead after QKV GEMM
  float* out     = (float*)d_out;

  // 0) RPE bias table + input splits
  bias_kernel<<<(H_*N_*N_ + 255)/256, 256, 0, stream>>>(rpe_table, rpe_index, biasT, rpe_m);
  split_img_kernel<<<(MB_*KB_*512 + 255)/256, 256, 0, stream>>>(x, ximg, M_, C_, MB_*KB_*512);
  split_img_kernel<<<(18*KB_*512 + 255)/256, 256, 0, stream>>>(qkv_w, wqkvimg, C3_, C_, 18*KB_*512);
  split_img_kernel<<<(6*KB_*512 + 255)/256, 256, 0, stream>>>(proj_w, wprojimg, C_, C_, 6*KB_*512);
  // 1) QKV projection -> bf16 Q/K/VT images (W-major)
  gemm3_qkv_kernel<<<dim3(MB_, C3_/128), 256, 0, stream>>>(wqkvimg, ximg, qkv_b, Qimg, Kimg, VTimg, KB_);
  // 2) template-block attention -> out_t
  attn_template_kernel<<<B_*H_, 256, 0, stream>>>(Qimg, Kimg, boxmask, rpe_table, rpe_index, out_t, rpe_m);
  // 3) factor GEMV
  factor_kernel<<<(B_*H_*NT_)/4, 256, 0, stream>>>(out_t, box_w, box_b, factor);
  // 4) MFMA attention -> attn image (hi/lo, overwrites x image)
  attn_mfma_kernel<<<B_*H_*4, 256, 0, stream>>>(Qimg, Kimg, VTimg, biasT, factor, attnimg);
  // 5) output projection (bf16x3 MFMA, fp32 out)
  gemm3_kernel<<<dim3(C_/128, MB_), 256, 0, stream>>>(attnimg, wprojimg, proj_b, out, KB_, C_, M_);
}

// Round 6
// 440.268 us; speedup vs baseline: 6.8450x; 1.1208x over previous
//
#include <hip/hip_runtime.h>
#include <hip/hip_bf16.h>

#define B_ 64
#define N_ 245
#define NT_ 49
#define H_ 12
#define HD_ 64
#define C_ 768
#define C3_ 2304
#define M_ (B_*N_)         // 15680 tokens
#define MP_ 15744          // padded to 123*128
#define MB_ 123
#define KB_ 24             // 768/32 k-blocks
#define SCALE_ 0.125f
#define RPE_MAX_ 1792
#define NPAD_ 256

typedef short short8 __attribute__((ext_vector_type(8)));
typedef float f32x4 __attribute__((ext_vector_type(4)));
typedef ushort us8 __attribute__((ext_vector_type(8)));
typedef ushort us4 __attribute__((ext_vector_type(4)));

__device__ __forceinline__ ushort f2bf(float f) {   // fp32 -> bf16 RTN
  unsigned u = __builtin_bit_cast(unsigned, f);
  u += 0x7fffu + ((u >> 16) & 1u);
  return (ushort)(u >> 16);
}
__device__ __forceinline__ float bf2f(ushort u) {
  return __builtin_bit_cast(float, ((unsigned)u) << 16);
}
// split a = hi + lo (both bf16; dropped error ~2^-16 relative)
__device__ __forceinline__ void split2(float a, ushort& hi, ushort& lo) {
  unsigned u = __builtin_bit_cast(unsigned, a);
  hi = (ushort)(u >> 16);
  float hf = __builtin_bit_cast(float, u & 0xffff0000u);
  lo = (ushort)(__builtin_bit_cast(unsigned, a - hf) >> 16);
}

// ---- pre-tiled pre-swizzled hi|lo image: [blk][row 128][hi 32 | lo 32] ----
__global__ __launch_bounds__(256) void split_img_kernel(
    const float* __restrict__ A, ushort* __restrict__ img, int rows, int K, int total)
{
  int idx = blockIdx.x*256 + threadIdx.x;
  if (idx >= total) return;
  const int ch = idx & 3;
  const int r  = (idx >> 2) & 127;
  const int t  = idx >> 9;
  const int KBl = K >> 5;
  const int kb = t % KBl, mb = t / KBl;
  const int m = mb*128 + r;
  float4 v0 = make_float4(0,0,0,0), v1 = make_float4(0,0,0,0);
  if (m < rows) {
    const float* p = A + (size_t)m*K + kb*32 + ch*8;
    v0 = *(const float4*)p; v1 = *(const float4*)(p+4);
  }
  float vals[8] = {v0.x,v0.y,v0.z,v0.w,v1.x,v1.y,v1.z,v1.w};
  us8 hv, lv;
  #pragma unroll
  for (int e = 0; e < 8; ++e) { ushort hh, ll; split2(vals[e], hh, ll); hv[e]=hh; lv[e]=ll; }
  ushort* base = img + ((size_t)t*128 + r)*64;
  const int sw = (ch ^ (r&7))*8;
  *(us8*)(base + sw)        = hv;
  *(us8*)(base + (sw ^ 32)) = lv;
}

// ---- stage one 16KB tile linearly into LDS ----
__device__ __forceinline__ void stage_tile(const ushort* __restrict__ src, ushort* dst,
                                           int wid, int lane) {
  #pragma unroll
  for (int t = 0; t < 4; ++t) {
    const int o = (wid*4 + t) * 512;
    __builtin_amdgcn_global_load_lds(
      (const __attribute__((address_space(1))) unsigned int*)(src + o + lane*8),
      (__attribute__((address_space(3))) unsigned int*)(dst + o),
      16, 0, 0);
  }
}

// ---- bf16x3 GEMM (token-major A): Co = A @ B^T + bias, fp32 out (proj) ----
__global__ __launch_bounds__(256) void gemm3_kernel(
    const ushort* __restrict__ Aimg, const ushort* __restrict__ Bimg,
    const float* __restrict__ bias, float* __restrict__ Co,
    int KB, int Nn, int M)
{
  __shared__ __align__(16) ushort lds[2][16384];
  const int tid = threadIdx.x, lane = tid & 63, wid = tid >> 6;
  const int g = lane >> 4, li = lane & 15;
  const int nb = blockIdx.x, mb = blockIdx.y;
  const int wr = (wid >> 1) * 64, wc = (wid & 1) * 64;

  const ushort* Abase = Aimg + (size_t)mb * KB * 8192;
  const ushort* Bbase = Bimg + (size_t)nb * KB * 8192;

  f32x4 acc[4][4];
  #pragma unroll
  for (int i = 0; i < 4; ++i)
    #pragma unroll
    for (int j = 0; j < 4; ++j) acc[i][j] = (f32x4){0.f,0.f,0.f,0.f};

  stage_tile(Abase, &lds[0][0],    wid, lane);
  stage_tile(Bbase, &lds[0][8192], wid, lane);
  __syncthreads();

  for (int kb = 0; kb < KB; ++kb) {
    const int cur = kb & 1;
    if (kb + 1 < KB) {
      stage_tile(Abase + (size_t)(kb+1)*8192, &lds[cur^1][0],    wid, lane);
      stage_tile(Bbase + (size_t)(kb+1)*8192, &lds[cur^1][8192], wid, lane);
    }
    short8 ah[4], al[4], bh[4], bl[4];
    #pragma unroll
    for (int t = 0; t < 4; ++t) {
      const int ra = wr + t*16 + li;
      const ushort* Ar = &lds[cur][ra*64];
      const int ca = (g ^ (ra & 7)) * 8;
      ah[t] = *(const short8*)(Ar + ca);
      al[t] = *(const short8*)(Ar + (ca ^ 32));
      const int rb = wc + t*16 + li;
      const ushort* Br = &lds[cur][8192 + rb*64];
      const int cb = (g ^ (rb & 7)) * 8;
      bh[t] = *(const short8*)(Br + cb);
      bl[t] = *(const short8*)(Br + (cb ^ 32));
    }
    #pragma unroll
    for (int i = 0; i < 4; ++i)
      #pragma unroll
      for (int j = 0; j < 4; ++j) {
        acc[i][j] = __builtin_amdgcn_mfma_f32_16x16x32_bf16(ah[i], bh[j], acc[i][j], 0,0,0);
        acc[i][j] = __builtin_amdgcn_mfma_f32_16x16x32_bf16(al[i], bh[j], acc[i][j], 0,0,0);
        acc[i][j] = __builtin_amdgcn_mfma_f32_16x16x32_bf16(ah[i], bl[j], acc[i][j], 0,0,0);
      }
    __syncthreads();
  }

  #pragma unroll
  for (int i = 0; i < 4; ++i) {
    const int m0 = mb*128 + wr + i*16 + g*4;
    #pragma unroll
    for (int j = 0; j < 4; ++j) {
      const int n = nb*128 + wc + j*16 + li;
      const float bv = bias[n];
      #pragma unroll
      for (int rr = 0; rr < 4; ++rr) {
        const int m = m0 + rr;
        if (m < M) Co[(size_t)m * Nn + n] = acc[i][j][rr] + bv;
      }
    }
  }
}

// ---- bf16x3 QKV GEMM (W-major A): writes bf16 Q/K/VT images directly ----
// Q is pre-scaled by SCALE_ (exact pow2). Grid: x=channel block (shares token panel).
__global__ __launch_bounds__(256) void gemm3_qkv_kernel(
    const ushort* __restrict__ Aimg, const ushort* __restrict__ Bimg,
    const float* __restrict__ bias,
    ushort* __restrict__ Qimg, ushort* __restrict__ Kimg, ushort* __restrict__ VTimg,
    int KB)
{
  __shared__ __align__(16) ushort lds[2][16384];
  const int tid = threadIdx.x, lane = tid & 63, wid = tid >> 6;
  const int g = lane >> 4, li = lane & 15;
  const int mb = blockIdx.x, nb = blockIdx.y;    // mb: channel block (fastest), nb: token block
  const int wr = (wid >> 1) * 64, wc = (wid & 1) * 64;

  const ushort* Abase = Aimg + (size_t)mb * KB * 8192;
  const ushort* Bbase = Bimg + (size_t)nb * KB * 8192;

  f32x4 acc[4][4];
  #pragma unroll
  for (int i = 0; i < 4; ++i)
    #pragma unroll
    for (int j = 0; j < 4; ++j) acc[i][j] = (f32x4){0.f,0.f,0.f,0.f};

  stage_tile(Abase, &lds[0][0],    wid, lane);
  stage_tile(Bbase, &lds[0][8192], wid, lane);
  __syncthreads();

  for (int kb = 0; kb < KB; ++kb) {
    const int cur = kb & 1;
    if (kb + 1 < KB) {
      stage_tile(Abase + (size_t)(kb+1)*8192, &lds[cur^1][0],    wid, lane);
      stage_tile(Bbase + (size_t)(kb+1)*8192, &lds[cur^1][8192], wid, lane);
    }
    short8 ah[4], al[4], bh[4], bl[4];
    #pragma unroll
    for (int t = 0; t < 4; ++t) {
      const int ra = wr + t*16 + li;
      const ushort* Ar = &lds[cur][ra*64];
      const int ca = (g ^ (ra & 7)) * 8;
      ah[t] = *(const short8*)(Ar + ca);
      al[t] = *(const short8*)(Ar + (ca ^ 32));
      const int rb = wc + t*16 + li;
      const ushort* Br = &lds[cur][8192 + rb*64];
      const int cb = (g ^ (rb & 7)) * 8;
      bh[t] = *(const short8*)(Br + cb);
      bl[t] = *(const short8*)(Br + (cb ^ 32));
    }
    #pragma unroll
    for (int i = 0; i < 4; ++i)
      #pragma unroll
      for (int j = 0; j < 4; ++j) {
        acc[i][j] = __builtin_amdgcn_mfma_f32_16x16x32_bf16(ah[i], bh[j], acc[i][j], 0,0,0);
        acc[i][j] = __builtin_amdgcn_mfma_f32_16x16x32_bf16(al[i], bh[j], acc[i][j], 0,0,0);
        acc[i][j] = __builtin_amdgcn_mfma_f32_16x16x32_bf16(ah[i], bl[j], acc[i][j], 0,0,0);
      }
    __syncthreads();
  }

  // epilogue: quad = channels ch0..ch0+3 at one token per (j,li)
  #pragma unroll
  for (int i = 0; i < 4; ++i) {
    const int ch0 = mb*128 + wr + i*16 + g*4;
    const int part = ch0 / 768;           // 0=q 1=k 2=v (uniform within quad/tile)
    const int rem  = ch0 - part*768;
    const int h = rem >> 6, d0 = rem & 63;
    const float b0 = bias[ch0+0], b1 = bias[ch0+1], b2 = bias[ch0+2], b3 = bias[ch0+3];
    #pragma unroll
    for (int j = 0; j < 4; ++j) {
      const int tok = nb*128 + wc + j*16 + li;
      if (tok < M_) {
        const int b = tok / 245;
        const int jl = tok - b*245;
        const int bh = b*H_ + h;
        if (part == 0) {
          us4 q4 = { f2bf((acc[i][j][0] + b0)*SCALE_), f2bf((acc[i][j][1] + b1)*SCALE_),
                     f2bf((acc[i][j][2] + b2)*SCALE_), f2bf((acc[i][j][3] + b3)*SCALE_) };
          *(us4*)(Qimg + ((size_t)bh*NPAD_ + jl)*64 + d0) = q4;
        } else if (part == 1) {
          us4 k4 = { f2bf(acc[i][j][0] + b0), f2bf(acc[i][j][1] + b1),
                     f2bf(acc[i][j][2] + b2), f2bf(acc[i][j][3] + b3) };
          *(us4*)(Kimg + ((size_t)bh*NPAD_ + jl)*64 + (d0 ^ ((jl&7)<<3))) = k4;
        } else {
          VTimg[((size_t)bh*64 + d0+0)*NPAD_ + (jl ^ (((d0+0)&7)<<3))] = f2bf(acc[i][j][0] + b0);
          VTimg[((size_t)bh*64 + d0+1)*NPAD_ + (jl ^ (((d0+1)&7)<<3))] = f2bf(acc[i][j][1] + b1);
          VTimg[((size_t)bh*64 + d0+2)*NPAD_ + (jl ^ (((d0+2)&7)<<3))] = f2bf(acc[i][j][2] + b2);
          VTimg[((size_t)bh*64 + d0+3)*NPAD_ + (jl ^ (((d0+3)&7)<<3))] = f2bf(acc[i][j][3] + b3);
        }
      }
    }
  }
}

// -------- G[b,ht,h,j] = sum_d box_w[h,ht*64+d] * boxmask[b,j,ht*64+d] --------
__global__ __launch_bounds__(256) void g_kernel(
    const float* __restrict__ boxmask, const float* __restrict__ box_w,
    float* __restrict__ G)
{
  __shared__ float bms[NT_][65];
  __shared__ float bws[H_][65];
  const int bx = blockIdx.x;       // b*12 + ht
  const int b = bx / H_, ht = bx % H_;
  const int tid = threadIdx.x;
  for (int idx = tid; idx < NT_*64; idx += 256) {
    int j = idx >> 6, d = idx & 63;
    bms[j][d] = boxmask[((size_t)(b*NT_ + j))*C_ + ht*64 + d];
  }
  for (int idx = tid; idx < H_*64; idx += 256) {
    int h = idx >> 6, d = idx & 63;
    bws[h][d] = box_w[(size_t)h*C_ + ht*64 + d];
  }
  __syncthreads();
  for (int o = tid; o < H_*64; o += 256) {
    int h = o >> 6, j = o & 63;
    float s = 0.f;
    if (j < NT_) {
      #pragma unroll
      for (int d = 0; d < 64; ++d) s = fmaf(bws[h][d], bms[j][d], s);
    }
    G[(size_t)bx*H_*64 + o] = s;
  }
}

// -------- template attention (MFMA) -> F_part[b,h,i,ht] = sum_j P[i,j]*G[b,ht,h,j] --------
__global__ __launch_bounds__(256) void tmpl_kernel(
    const ushort* __restrict__ Qimg, const ushort* __restrict__ Kimg,
    const float* __restrict__ G, const float* __restrict__ biasT,
    float* __restrict__ F_part)
{
  __shared__ __align__(16) ushort kt_lds[64*64];   // first 64 K rows (swizzled image)
  __shared__ __align__(16) float Gs[H_*64];
  const int bx = blockIdx.x;       // b*12 + ht
  const int b = bx / H_, ht = bx % H_;
  const int tid = threadIdx.x, lane = tid & 63, wid = tid >> 6;
  const int g = lane >> 4, li = lane & 15;

  const ushort* Kb = Kimg + (size_t)bx*NPAD_*64;
  #pragma unroll
  for (int t = 0; t < 2; ++t) {
    const int o = (t*4 + wid) * 512;
    __builtin_amdgcn_global_load_lds(
      (const __attribute__((address_space(1))) unsigned int*)(Kb + o + lane*8),
      (__attribute__((address_space(3))) unsigned int*)(kt_lds + o), 16, 0, 0);
  }
  for (int idx = tid; idx < H_*64; idx += 256) Gs[idx] = G[(size_t)bx*H_*64 + idx];

  const int i = wid*16 + li;       // q-row 0..63 (template rows are 0..48)
  short8 bq[2];
  {
    const ushort* qp = Qimg + ((size_t)bx*NPAD_ + i)*64;   // Q pre-scaled
    bq[0] = *(const short8*)(qp + g*8);
    bq[1] = *(const short8*)(qp + 32 + g*8);
  }
  __syncthreads();

  f32x4 sacc[4];
  #pragma unroll
  for (int jt = 0; jt < 4; ++jt) sacc[jt] = (f32x4){0.f,0.f,0.f,0.f};
  #pragma unroll
  for (int jt = 0; jt < 4; ++jt) {
    int jr = jt*16 + li;
    #pragma unroll
    for (int kc = 0; kc < 2; ++kc) {
      short8 af = *(const short8*)(kt_lds + jr*64 + ((kc*32 + g*8) ^ ((jr&7)<<3)));
      sacc[jt] = __builtin_amdgcn_mfma_f32_16x16x32_bf16(af, bq[kc], sacc[jt], 0, 0, 0);
    }
  }

  const float* bT = biasT + (size_t)ht*NPAD_*NPAD_;
  float mloc = 0.f;                 // masked zeros join the max
  #pragma unroll
  for (int jt = 0; jt < 4; ++jt)
    #pragma unroll
    for (int r = 0; r < 4; ++r) {
      int j = jt*16 + g*4 + r;
      float sv = (j < NT_) ? (sacc[jt][r] + bT[(size_t)j*NPAD_ + i]) : -1e30f;
      sacc[jt][r] = sv;
      mloc = fmaxf(mloc, sv);
    }
  mloc = fmaxf(mloc, __shfl_xor(mloc, 16));
  mloc = fmaxf(mloc, __shfl_xor(mloc, 32));
  float ssum = 0.f;
  #pragma unroll
  for (int jt = 0; jt < 4; ++jt)
    #pragma unroll
    for (int r = 0; r < 4; ++r) {
      int j = jt*16 + g*4 + r;
      float e = (j < NT_) ? __expf(sacc[jt][r] - mloc) : 0.f;
      sacc[jt][r] = e;
      ssum += e;
    }
  ssum += __shfl_xor(ssum, 16);
  ssum += __shfl_xor(ssum, 32);
  const float inv = 1.f / (ssum + 196.f * __expf(-mloc));   // 196 masked exp(0-mx)

  float F[12];
  #pragma unroll
  for (int h = 0; h < 12; ++h) F[h] = 0.f;
  #pragma unroll
  for (int jt = 0; jt < 4; ++jt) {
    f32x4 p = sacc[jt] * inv;
    #pragma unroll
    for (int h = 0; h < 12; ++h) {
      const float4 g4 = *(const float4*)(&Gs[h*64 + jt*16 + g*4]);
      F[h] = fmaf(p[0], g4.x, fmaf(p[1], g4.y, fmaf(p[2], g4.z, fmaf(p[3], g4.w, F[h]))));
    }
  }
  #pragma unroll
  for (int h = 0; h < 12; ++h) {
    F[h] += __shfl_xor(F[h], 16);
    F[h] += __shfl_xor(F[h], 32);
  }
  if (lane < 16 && i < NT_) {
    #pragma unroll
    for (int h = 0; h < 12; ++h)
      F_part[((size_t)(b*H_ + h)*NT_ + i)*12 + ht] = F[h];
  }
}

// -------- dense transposed RPE bias --------
__global__ __launch_bounds__(256) void bias_kernel(
    const float* __restrict__ rpe_table, const int* __restrict__ rpe_index,
    float* __restrict__ biasT, int rpe_m)
{
  int idx = blockIdx.x * 256 + threadIdx.x;
  if (idx >= H_*N_*N_) return;
  int h = idx / (N_*N_);
  int rem = idx % (N_*N_);
  int j = rem / N_;
  int i = rem % N_;
  biasT[((size_t)h*NPAD_ + j)*NPAD_ + i] = rpe_table[h*rpe_m + rpe_index[i*N_ + j]];
}

// -------- MFMA flash attention; hi/lo image out via LDS-transposed us8 stores --------
__global__ __launch_bounds__(256) void attn_mfma_kernel(
    const ushort* __restrict__ Qimg, const ushort* __restrict__ Kimg,
    const ushort* __restrict__ VTimg, const float* __restrict__ biasT,
    const float* __restrict__ F_part, const float* __restrict__ box_b,
    ushort* __restrict__ attnimg)
{
  __shared__ __align__(16) ushort kp_lds[NPAD_*64];   // K image; then P; then O-transpose
  __shared__ __align__(16) ushort vt_lds[64*NPAD_];   // V^T image
  const int bx = blockIdx.x;
  const int bh = bx >> 2, rb = bx & 3;
  const int b = bh / H_, h = bh % H_;
  const int tid = threadIdx.x, lane = tid & 63, wid = tid >> 6;
  const int g = lane >> 4, li = lane & 15;

  const ushort* Kb = Kimg  + (size_t)bh*16384;
  const ushort* Vb = VTimg + (size_t)bh*16384;
  #pragma unroll
  for (int t = 0; t < 8; ++t) {
    const int o = (t*4 + wid) * 512;
    __builtin_amdgcn_global_load_lds(
      (const __attribute__((address_space(1))) unsigned int*)(Kb + o + lane*8),
      (__attribute__((address_space(3))) unsigned int*)(kp_lds + o), 16, 0, 0);
    __builtin_amdgcn_global_load_lds(
      (const __attribute__((address_space(1))) unsigned int*)(Vb + o + lane*8),
      (__attribute__((address_space(3))) unsigned int*)(vt_lds + o), 16, 0, 0);
  }

  const int i0 = rb*64 + wid*16;
  const int ig = i0 + li;
  const int iq = (ig < N_) ? ig : (N_-1);
  short8 bq[2];
  {
    const ushort* qp = Qimg + ((size_t)bh*NPAD_ + iq)*64;   // Q pre-scaled
    bq[0] = *(const short8*)(qp + g*8);
    bq[1] = *(const short8*)(qp + 32 + g*8);
  }
  __syncthreads();

  f32x4 sacc[16];
  #pragma unroll
  for (int jt = 0; jt < 16; ++jt) sacc[jt] = (f32x4){0.f,0.f,0.f,0.f};
  #pragma unroll
  for (int jt = 0; jt < 16; ++jt) {
    int jr = jt*16 + li;
    #pragma unroll
    for (int kc = 0; kc < 2; ++kc) {
      short8 af = *(const short8*)(kp_lds + jr*64 + ((kc*32 + g*8) ^ ((jr&7)<<3)));
      sacc[jt] = __builtin_amdgcn_mfma_f32_16x16x32_bf16(af, bq[kc], sacc[jt], 0, 0, 0);
    }
  }
  __syncthreads();   // all waves done reading K; kp_lds becomes P

  float fac = 1.0f;
  if (ig < NT_) {
    const float* fp = F_part + ((size_t)bh*NT_ + ig)*12;
    float4 f0 = *(const float4*)fp;
    float4 f1 = *(const float4*)(fp+4);
    float4 f2 = *(const float4*)(fp+8);
    fac = box_b[h] + f0.x+f0.y+f0.z+f0.w + f1.x+f1.y+f1.z+f1.w + f2.x+f2.y+f2.z+f2.w;
  }
  const float* bT = biasT + (size_t)h*NPAD_*NPAD_;
  float mloc = -1e30f;
  #pragma unroll
  for (int jt = 0; jt < 16; ++jt) {
    #pragma unroll
    for (int r = 0; r < 4; ++r) {
      int j = jt*16 + g*4 + r;
      float sv = sacc[jt][r] + bT[(size_t)j*NPAD_ + i0 + li];
      if (ig < NT_ && j >= NT_) sv *= fac;
      if (j >= N_) sv = -1e30f;
      sacc[jt][r] = sv;
      mloc = fmaxf(mloc, sv);
    }
  }
  mloc = fmaxf(mloc, __shfl_xor(mloc, 16));
  mloc = fmaxf(mloc, __shfl_xor(mloc, 32));
  float ssum = 0.f;
  #pragma unroll
  for (int jt = 0; jt < 16; ++jt) {
    #pragma unroll
    for (int r = 0; r < 4; ++r) {
      float e = __expf(sacc[jt][r] - mloc);
      sacc[jt][r] = e;
      ssum += e;
    }
  }
  ssum += __shfl_xor(ssum, 16);
  ssum += __shfl_xor(ssum, 32);
  const float inv = 1.0f / ssum;

  ushort* pbase = kp_lds + wid*4096 + li*256;
  const int swz = (li & 7) << 3;
  #pragma unroll
  for (int jt = 0; jt < 16; ++jt) {
    unsigned w0 = (unsigned)f2bf(sacc[jt][0]*inv) | ((unsigned)f2bf(sacc[jt][1]*inv) << 16);
    unsigned w1 = (unsigned)f2bf(sacc[jt][2]*inv) | ((unsigned)f2bf(sacc[jt][3]*inv) << 16);
    *(uint2*)(pbase + ((jt*16 + g*4) ^ swz)) = make_uint2(w0, w1);
  }

  f32x4 oacc[4];
  #pragma unroll
  for (int dt = 0; dt < 4; ++dt) oacc[dt] = (f32x4){0.f,0.f,0.f,0.f};
  #pragma unroll
  for (int jc = 0; jc < 8; ++jc) {
    short8 pf = *(const short8*)(pbase + ((jc*32 + g*8) ^ swz));
    #pragma unroll
    for (int dt = 0; dt < 4; ++dt) {
      int row = dt*16 + li;
      short8 vf = *(const short8*)(vt_lds + row*NPAD_ + ((jc*32 + g*8) ^ ((row&7)<<3)));
      oacc[dt] = __builtin_amdgcn_mfma_f32_16x16x32_bf16(vf, pf, oacc[dt], 0, 0, 0);
    }
  }
  __syncthreads();   // PV complete everywhere; reuse per-wave P region for O transpose

  // ---- per-wave LDS transpose: [d 64][tok 16] f32 stride 19, then coalesced us8 stores ----
  float* tb = (float*)(kp_lds + wid*4096);
  #pragma unroll
  for (int dt = 0; dt < 4; ++dt)
    #pragma unroll
    for (int rr = 0; rr < 4; ++rr)
      tb[(dt*16 + g*4 + rr)*19 + li] = oacc[dt][rr];

  const int rtok = lane >> 2, cg = lane & 3;
  const int tokl = i0 + rtok;
  if (tokl < N_) {
    const int m = b*N_ + tokl;
    const int mbm = m >> 7, rr_ = m & 127, rx = rr_ & 7;
    const int kbb = h*2 + (cg >> 1);
    ushort* baseimg = attnimg + (((size_t)(mbm*KB_ + kbb))*128 + rr_)*64;
    #pragma unroll
    for (int half = 0; half < 2; ++half) {
      us8 hv, lv;
      #pragma unroll
      for (int e = 0; e < 8; ++e) {
        float v = tb[(cg*16 + half*8 + e)*19 + rtok];
        ushort hh, ll; split2(v, hh, ll);
        hv[e] = hh; lv[e] = ll;
      }
      const int c0 = (cg & 1)*2 + half;
      *(us8*)(baseimg + ((c0 ^ rx) * 8))        = hv;
      *(us8*)(baseimg + (((c0 ^ 4) ^ rx) * 8))  = lv;
    }
  }
}

extern "C" void kernel_launch(void* const* d_in, const int* in_sizes, int n_in,
                              void* d_out, int out_size, void* d_ws, size_t ws_size,
                              hipStream_t stream)
{
  const float* x         = (const float*)d_in[0];
  const float* boxmask   = (const float*)d_in[1];
  const float* qkv_w     = (const float*)d_in[2];
  const float* qkv_b     = (const float*)d_in[3];
  const float* proj_w    = (const float*)d_in[4];
  const float* proj_b    = (const float*)d_in[5];
  const float* box_w     = (const float*)d_in[6];
  const float* box_b     = (const float*)d_in[7];
  const float* rpe_table = (const float*)d_in[8];
  const int*   rpe_index = (const int*)d_in[9];
  const int rpe_m = in_sizes[8] / H_;   // 1698

  float* ws      = (float*)d_ws;
  float* G       = ws;                                   // 589,824 f
  float* F_part  = G + (size_t)B_*H_*H_*64;              // 451,584 f
  float* biasT   = F_part + (size_t)B_*H_*NT_*12;        // 786,432 f
  ushort* ximg    = (ushort*)(biasT + (size_t)H_*NPAD_*NPAD_);
  ushort* wqkvimg  = ximg     + (size_t)MP_*C_*2;        // 24,182,784 us
  ushort* wprojimg = wqkvimg  + (size_t)C3_*C_*2;        // 3,538,944 us
  ushort* Qimg     = wprojimg + (size_t)C_*C_*2;         // 1,179,648 us
  ushort* Kimg     = Qimg     + (size_t)B_*H_*NPAD_*64;  // 12,582,912 us each
  ushort* VTimg    = Kimg     + (size_t)B_*H_*NPAD_*64;
  ushort* attnimg  = ximg;   // alias: x image dead after QKV GEMM
  float* out     = (float*)d_out;

  // 0) RPE bias table, G precompute, input splits
  bias_kernel<<<(H_*N_*N_ + 255)/256, 256, 0, stream>>>(rpe_table, rpe_index, biasT, rpe_m);
  g_kernel<<<B_*H_, 256, 0, stream>>>(boxmask, box_w, G);
  split_img_kernel<<<(MB_*KB_*512 + 255)/256, 256, 0, stream>>>(x, ximg, M_, C_, MB_*KB_*512);
  split_img_kernel<<<(18*KB_*512 + 255)/256, 256, 0, stream>>>(qkv_w, wqkvimg, C3_, C_, 18*KB_*512);
  split_img_kernel<<<(6*KB_*512 + 255)/256, 256, 0, stream>>>(proj_w, wprojimg, C_, C_, 6*KB_*512);
  // 1) QKV projection -> bf16 Q/K/VT images (channel-block fastest for x-panel sharing)
  gemm3_qkv_kernel<<<dim3(C3_/128, MB_), 256, 0, stream>>>(wqkvimg, ximg, qkv_b, Qimg, Kimg, VTimg, KB_);
  // 2) template attention (MFMA) -> F_part
  tmpl_kernel<<<B_*H_, 256, 0, stream>>>(Qimg, Kimg, G, biasT, F_part);
  // 3) MFMA attention -> attn image (factor folded from F_part)
  attn_mfma_kernel<<<B_*H_*4, 256, 0, stream>>>(Qimg, Kimg, VTimg, biasT, F_part, box_b, attnimg);
  // 4) output projection (bf16x3 MFMA, fp32 out)
  gemm3_kernel<<<dim3(C_/128, MB_), 256, 0, stream>>>(attnimg, wprojimg, proj_b, out, KB_, C_, M_);
}

// Round 8
// 418.815 us; speedup vs baseline: 7.1956x; 1.0512x over previous
//
#include <hip/hip_runtime.h>
#include <hip/hip_bf16.h>

#define B_ 64
#define N_ 245
#define NT_ 49
#define H_ 12
#define HD_ 64
#define C_ 768
#define C3_ 2304
#define M_ (B_*N_)         // 15680 tokens
#define MP_ 15744          // padded to 123*128
#define MB_ 123
#define KB_ 24             // 768/32 k-blocks
#define SCALE_ 0.125f
#define NPAD_ 256
#define NWG_QKV_ (18*123)  // 2214
#define NWG_PROJ_ (6*123)  // 738

typedef short short8 __attribute__((ext_vector_type(8)));
typedef float f32x4 __attribute__((ext_vector_type(4)));
typedef ushort us8 __attribute__((ext_vector_type(8)));
typedef ushort us4 __attribute__((ext_vector_type(4)));

__device__ __forceinline__ ushort f2bf(float f) {   // fp32 -> bf16 RTN
  unsigned u = __builtin_bit_cast(unsigned, f);
  u += 0x7fffu + ((u >> 16) & 1u);
  return (ushort)(u >> 16);
}
__device__ __forceinline__ float bf2f(ushort u) {
  return __builtin_bit_cast(float, ((unsigned)u) << 16);
}
// split a = hi + lo (both bf16; dropped error ~2^-16 relative)
__device__ __forceinline__ void split2(float a, ushort& hi, ushort& lo) {
  unsigned u = __builtin_bit_cast(unsigned, a);
  hi = (ushort)(u >> 16);
  float hf = __builtin_bit_cast(float, u & 0xffff0000u);
  lo = (ushort)(__builtin_bit_cast(unsigned, a - hf) >> 16);
}
// m204 bijective XCD swizzle
__device__ __forceinline__ int xcd_swz(int orig, int nwg) {
  const int q = nwg >> 3, r = nwg & 7;
  const int xcd = orig & 7, off = orig >> 3;
  return (xcd < r ? xcd*(q+1) : r*(q+1) + (xcd-r)*q) + off;
}

// ---- split one 8-elem chunk into the pre-tiled pre-swizzled hi|lo image ----
__device__ __forceinline__ void split_dev(
    const float* __restrict__ A, ushort* __restrict__ img, int rows, int K, int idx)
{
  const int ch = idx & 3;
  const int r  = (idx >> 2) & 127;
  const int t  = idx >> 9;
  const int KBl = K >> 5;
  const int kb = t % KBl, mb = t / KBl;
  const int m = mb*128 + r;
  float4 v0 = make_float4(0,0,0,0), v1 = make_float4(0,0,0,0);
  if (m < rows) {
    const float* p = A + (size_t)m*K + kb*32 + ch*8;
    v0 = *(const float4*)p; v1 = *(const float4*)(p+4);
  }
  float vals[8] = {v0.x,v0.y,v0.z,v0.w,v1.x,v1.y,v1.z,v1.w};
  us8 hv, lv;
  #pragma unroll
  for (int e = 0; e < 8; ++e) { ushort hh, ll; split2(vals[e], hh, ll); hv[e]=hh; lv[e]=ll; }
  ushort* base = img + ((size_t)t*128 + r)*64;
  const int sw = (ch ^ (r&7))*8;
  *(us8*)(base + sw)        = hv;
  *(us8*)(base + (sw ^ 32)) = lv;
}

// ---- merged prep: x/w splits + bf16 biasT gather + G GEMV ----
#define PREP_X_   5904   // 123*24*512/256
#define PREP_WQ_  864    // 18*24*512/256
#define PREP_WP_  288    // 6*24*512/256
#define PREP_BT_  2814   // ceil(12*245*245/256)
#define PREP_G_   768    // B_*H_
__global__ __launch_bounds__(256) void prep_kernel(
    const float* __restrict__ x, const float* __restrict__ qkv_w,
    const float* __restrict__ proj_w, const float* __restrict__ rpe_table,
    const int* __restrict__ rpe_index, const float* __restrict__ boxmask,
    const float* __restrict__ box_w,
    ushort* __restrict__ ximg, ushort* __restrict__ wqkvimg, ushort* __restrict__ wprojimg,
    ushort* __restrict__ biasTb, float* __restrict__ G, int rpe_m)
{
  __shared__ float bms[NT_][65];
  __shared__ float bws[H_][65];
  int id = blockIdx.x;
  const int tid = threadIdx.x;
  if (id < PREP_X_)  { split_dev(x,      ximg,     M_,  C_, id*256 + tid); return; }
  id -= PREP_X_;
  if (id < PREP_WQ_) { split_dev(qkv_w,  wqkvimg,  C3_, C_, id*256 + tid); return; }
  id -= PREP_WQ_;
  if (id < PREP_WP_) { split_dev(proj_w, wprojimg, C_,  C_, id*256 + tid); return; }
  id -= PREP_WP_;
  if (id < PREP_BT_) {
    int idx = id*256 + tid;
    if (idx < H_*N_*N_) {
      int h = idx / (N_*N_);
      int rem = idx % (N_*N_);
      int j = rem / N_, i = rem % N_;
      biasTb[((size_t)h*NPAD_ + j)*NPAD_ + i] = f2bf(rpe_table[h*rpe_m + rpe_index[i*N_ + j]]);
    }
    return;
  }
  id -= PREP_BT_;
  // G role: id = b*12 + ht
  {
    const int b = id / H_, ht = id % H_;
    for (int idx = tid; idx < NT_*64; idx += 256) {
      int j = idx >> 6, d = idx & 63;
      bms[j][d] = boxmask[((size_t)(b*NT_ + j))*C_ + ht*64 + d];
    }
    for (int idx = tid; idx < H_*64; idx += 256) {
      int h = idx >> 6, d = idx & 63;
      bws[h][d] = box_w[(size_t)h*C_ + ht*64 + d];
    }
    __syncthreads();
    for (int o = tid; o < H_*64; o += 256) {
      int h = o >> 6, j = o & 63;
      float s = 0.f;
      if (j < NT_) {
        #pragma unroll
        for (int d = 0; d < 64; ++d) s = fmaf(bws[h][d], bms[j][d], s);
      }
      G[(size_t)id*H_*64 + o] = s;
    }
  }
}

// ---- stage one 16KB tile linearly into LDS ----
__device__ __forceinline__ void stage_tile(const ushort* __restrict__ src, ushort* dst,
                                           int wid, int lane) {
  #pragma unroll
  for (int t = 0; t < 4; ++t) {
    const int o = (wid*4 + t) * 512;
    __builtin_amdgcn_global_load_lds(
      (const __attribute__((address_space(1))) unsigned int*)(src + o + lane*8),
      (__attribute__((address_space(3))) unsigned int*)(dst + o),
      16, 0, 0);
  }
}

// ---- bf16x3 GEMM (token-major A): Co = A @ B^T + bias, fp32 out (proj) ----
__global__ __launch_bounds__(256) void gemm3_kernel(
    const ushort* __restrict__ Aimg, const ushort* __restrict__ Bimg,
    const float* __restrict__ bias, float* __restrict__ Co,
    int KB, int Nn, int M)
{
  __shared__ __align__(16) ushort lds[2][16384];
  const int tid = threadIdx.x, lane = tid & 63, wid = tid >> 6;
  const int g = lane >> 4, li = lane & 15;
  const int sid = xcd_swz(blockIdx.x, NWG_PROJ_);
  const int nb = sid % 6, mb = sid / 6;
  const int wr = (wid >> 1) * 64, wc = (wid & 1) * 64;

  const ushort* Abase = Aimg + (size_t)mb * KB * 8192;
  const ushort* Bbase = Bimg + (size_t)nb * KB * 8192;

  f32x4 acc[4][4];
  #pragma unroll
  for (int i = 0; i < 4; ++i)
    #pragma unroll
    for (int j = 0; j < 4; ++j) acc[i][j] = (f32x4){0.f,0.f,0.f,0.f};

  stage_tile(Abase, &lds[0][0],    wid, lane);
  stage_tile(Bbase, &lds[0][8192], wid, lane);
  __syncthreads();

  for (int kb = 0; kb < KB; ++kb) {
    const int cur = kb & 1;
    if (kb + 1 < KB) {
      stage_tile(Abase + (size_t)(kb+1)*8192, &lds[cur^1][0],    wid, lane);
      stage_tile(Bbase + (size_t)(kb+1)*8192, &lds[cur^1][8192], wid, lane);
    }
    short8 ah[4], al[4], bh[4], bl[4];
    #pragma unroll
    for (int t = 0; t < 4; ++t) {
      const int ra = wr + t*16 + li;
      const ushort* Ar = &lds[cur][ra*64];
      const int ca = (g ^ (ra & 7)) * 8;
      ah[t] = *(const short8*)(Ar + ca);
      al[t] = *(const short8*)(Ar + (ca ^ 32));
      const int rb = wc + t*16 + li;
      const ushort* Br = &lds[cur][8192 + rb*64];
      const int cb = (g ^ (rb & 7)) * 8;
      bh[t] = *(const short8*)(Br + cb);
      bl[t] = *(const short8*)(Br + (cb ^ 32));
    }
    #pragma unroll
    for (int i = 0; i < 4; ++i)
      #pragma unroll
      for (int j = 0; j < 4; ++j) {
        acc[i][j] = __builtin_amdgcn_mfma_f32_16x16x32_bf16(ah[i], bh[j], acc[i][j], 0,0,0);
        acc[i][j] = __builtin_amdgcn_mfma_f32_16x16x32_bf16(al[i], bh[j], acc[i][j], 0,0,0);
        acc[i][j] = __builtin_amdgcn_mfma_f32_16x16x32_bf16(ah[i], bl[j], acc[i][j], 0,0,0);
      }
    __syncthreads();
  }

  #pragma unroll
  for (int i = 0; i < 4; ++i) {
    const int m0 = mb*128 + wr + i*16 + g*4;
    #pragma unroll
    for (int j = 0; j < 4; ++j) {
      const int n = nb*128 + wc + j*16 + li;
      const float bv = bias[n];
      #pragma unroll
      for (int rr = 0; rr < 4; ++rr) {
        const int m = m0 + rr;
        if (m < M) Co[(size_t)m * Nn + n] = acc[i][j][rr] + bv;
      }
    }
  }
}

// ---- bf16x3 QKV GEMM (W-major A): writes bf16 Q/K/VT images directly ----
__global__ __launch_bounds__(256) void gemm3_qkv_kernel(
    const ushort* __restrict__ Aimg, const ushort* __restrict__ Bimg,
    const float* __restrict__ bias,
    ushort* __restrict__ Qimg, ushort* __restrict__ Kimg, ushort* __restrict__ VTimg,
    int KB)
{
  __shared__ __align__(16) ushort lds[2][16384];
  const int tid = threadIdx.x, lane = tid & 63, wid = tid >> 6;
  const int g = lane >> 4, li = lane & 15;
  const int sid = xcd_swz(blockIdx.x, NWG_QKV_);
  const int mb = sid % 18, nb = sid / 18;   // mb: channel block (fastest), nb: token block
  const int wr = (wid >> 1) * 64, wc = (wid & 1) * 64;

  const ushort* Abase = Aimg + (size_t)mb * KB * 8192;
  const ushort* Bbase = Bimg + (size_t)nb * KB * 8192;

  f32x4 acc[4][4];
  #pragma unroll
  for (int i = 0; i < 4; ++i)
    #pragma unroll
    for (int j = 0; j < 4; ++j) acc[i][j] = (f32x4){0.f,0.f,0.f,0.f};

  stage_tile(Abase, &lds[0][0],    wid, lane);
  stage_tile(Bbase, &lds[0][8192], wid, lane);
  __syncthreads();

  for (int kb = 0; kb < KB; ++kb) {
    const int cur = kb & 1;
    if (kb + 1 < KB) {
      stage_tile(Abase + (size_t)(kb+1)*8192, &lds[cur^1][0],    wid, lane);
      stage_tile(Bbase + (size_t)(kb+1)*8192, &lds[cur^1][8192], wid, lane);
    }
    short8 ah[4], al[4], bh[4], bl[4];
    #pragma unroll
    for (int t = 0; t < 4; ++t) {
      const int ra = wr + t*16 + li;
      const ushort* Ar = &lds[cur][ra*64];
      const int ca = (g ^ (ra & 7)) * 8;
      ah[t] = *(const short8*)(Ar + ca);
      al[t] = *(const short8*)(Ar + (ca ^ 32));
      const int rb = wc + t*16 + li;
      const ushort* Br = &lds[cur][8192 + rb*64];
      const int cb = (g ^ (rb & 7)) * 8;
      bh[t] = *(const short8*)(Br + cb);
      bl[t] = *(const short8*)(Br + (cb ^ 32));
    }
    #pragma unroll
    for (int i = 0; i < 4; ++i)
      #pragma unroll
      for (int j = 0; j < 4; ++j) {
        acc[i][j] = __builtin_amdgcn_mfma_f32_16x16x32_bf16(ah[i], bh[j], acc[i][j], 0,0,0);
        acc[i][j] = __builtin_amdgcn_mfma_f32_16x16x32_bf16(al[i], bh[j], acc[i][j], 0,0,0);
        acc[i][j] = __builtin_amdgcn_mfma_f32_16x16x32_bf16(ah[i], bl[j], acc[i][j], 0,0,0);
      }
    __syncthreads();
  }

  // epilogue: quad = channels ch0..ch0+3 at one token per (j,li)
  #pragma unroll
  for (int i = 0; i < 4; ++i) {
    const int ch0 = mb*128 + wr + i*16 + g*4;
    const int part = ch0 / 768;           // 0=q 1=k 2=v (uniform within quad/tile)
    const int rem  = ch0 - part*768;
    const int h = rem >> 6, d0 = rem & 63;
    const float b0 = bias[ch0+0], b1 = bias[ch0+1], b2 = bias[ch0+2], b3 = bias[ch0+3];
    #pragma unroll
    for (int j = 0; j < 4; ++j) {
      const int tok = nb*128 + wc + j*16 + li;
      if (tok < M_) {
        const int b = tok / 245;
        const int jl = tok - b*245;
        const int bh = b*H_ + h;
        if (part == 0) {
          us4 q4 = { f2bf((acc[i][j][0] + b0)*SCALE_), f2bf((acc[i][j][1] + b1)*SCALE_),
                     f2bf((acc[i][j][2] + b2)*SCALE_), f2bf((acc[i][j][3] + b3)*SCALE_) };
          *(us4*)(Qimg + ((size_t)bh*NPAD_ + jl)*64 + d0) = q4;
        } else if (part == 1) {
          us4 k4 = { f2bf(acc[i][j][0] + b0), f2bf(acc[i][j][1] + b1),
                     f2bf(acc[i][j][2] + b2), f2bf(acc[i][j][3] + b3) };
          *(us4*)(Kimg + ((size_t)bh*NPAD_ + jl)*64 + (d0 ^ ((jl&7)<<3))) = k4;
        } else {
          VTimg[((size_t)bh*64 + d0+0)*NPAD_ + (jl ^ (((d0+0)&7)<<3))] = f2bf(acc[i][j][0] + b0);
          VTimg[((size_t)bh*64 + d0+1)*NPAD_ + (jl ^ (((d0+1)&7)<<3))] = f2bf(acc[i][j][1] + b1);
          VTimg[((size_t)bh*64 + d0+2)*NPAD_ + (jl ^ (((d0+2)&7)<<3))] = f2bf(acc[i][j][2] + b2);
          VTimg[((size_t)bh*64 + d0+3)*NPAD_ + (jl ^ (((d0+3)&7)<<3))] = f2bf(acc[i][j][3] + b3);
        }
      }
    }
  }
}

// -------- template attention (MFMA) -> F_part[b,h,i,ht] = sum_j P[i,j]*G[b,ht,h,j] --------
__global__ __launch_bounds__(256) void tmpl_kernel(
    const ushort* __restrict__ Qimg, const ushort* __restrict__ Kimg,
    const float* __restrict__ G, const ushort* __restrict__ biasTb,
    float* __restrict__ F_part)
{
  __shared__ __align__(16) ushort kt_lds[64*64];   // first 64 K rows (swizzled image)
  __shared__ __align__(16) float Gs[H_*64];
  const int bx = blockIdx.x;       // b*12 + ht
  const int b = bx / H_, ht = bx % H_;
  const int tid = threadIdx.x, lane = tid & 63, wid = tid >> 6;
  const int g = lane >> 4, li = lane & 15;

  const ushort* Kb = Kimg + (size_t)bx*NPAD_*64;
  #pragma unroll
  for (int t = 0; t < 2; ++t) {
    const int o = (t*4 + wid) * 512;
    __builtin_amdgcn_global_load_lds(
      (const __attribute__((address_space(1))) unsigned int*)(Kb + o + lane*8),
      (__attribute__((address_space(3))) unsigned int*)(kt_lds + o), 16, 0, 0);
  }
  for (int idx = tid; idx < H_*64; idx += 256) Gs[idx] = G[(size_t)bx*H_*64 + idx];

  const int i = wid*16 + li;       // q-row 0..63 (template rows are 0..48)
  short8 bq[2];
  {
    const ushort* qp = Qimg + ((size_t)bx*NPAD_ + i)*64;   // Q pre-scaled
    bq[0] = *(const short8*)(qp + g*8);
    bq[1] = *(const short8*)(qp + 32 + g*8);
  }
  __syncthreads();

  f32x4 sacc[4];
  #pragma unroll
  for (int jt = 0; jt < 4; ++jt) sacc[jt] = (f32x4){0.f,0.f,0.f,0.f};
  #pragma unroll
  for (int jt = 0; jt < 4; ++jt) {
    int jr = jt*16 + li;
    #pragma unroll
    for (int kc = 0; kc < 2; ++kc) {
      short8 af = *(const short8*)(kt_lds + jr*64 + ((kc*32 + g*8) ^ ((jr&7)<<3)));
      sacc[jt] = __builtin_amdgcn_mfma_f32_16x16x32_bf16(af, bq[kc], sacc[jt], 0, 0, 0);
    }
  }

  const ushort* bT = biasTb + (size_t)ht*NPAD_*NPAD_;
  float mloc = 0.f;                 // masked zeros join the max
  #pragma unroll
  for (int jt = 0; jt < 4; ++jt)
    #pragma unroll
    for (int r = 0; r < 4; ++r) {
      int j = jt*16 + g*4 + r;
      float sv = (j < NT_) ? (sacc[jt][r] + bf2f(bT[(size_t)j*NPAD_ + i])) : -1e30f;
      sacc[jt][r] = sv;
      mloc = fmaxf(mloc, sv);
    }
  mloc = fmaxf(mloc, __shfl_xor(mloc, 16));
  mloc = fmaxf(mloc, __shfl_xor(mloc, 32));
  float ssum = 0.f;
  #pragma unroll
  for (int jt = 0; jt < 4; ++jt)
    #pragma unroll
    for (int r = 0; r < 4; ++r) {
      int j = jt*16 + g*4 + r;
      float e = (j < NT_) ? __expf(sacc[jt][r] - mloc) : 0.f;
      sacc[jt][r] = e;
      ssum += e;
    }
  ssum += __shfl_xor(ssum, 16);
  ssum += __shfl_xor(ssum, 32);
  const float inv = 1.f / (ssum + 196.f * __expf(-mloc));   // 196 masked exp(0-mx)

  float F[12];
  #pragma unroll
  for (int h = 0; h < 12; ++h) F[h] = 0.f;
  #pragma unroll
  for (int jt = 0; jt < 4; ++jt) {
    f32x4 p = sacc[jt] * inv;
    #pragma unroll
    for (int h = 0; h < 12; ++h) {
      const float4 g4 = *(const float4*)(&Gs[h*64 + jt*16 + g*4]);
      F[h] = fmaf(p[0], g4.x, fmaf(p[1], g4.y, fmaf(p[2], g4.z, fmaf(p[3], g4.w, F[h]))));
    }
  }
  #pragma unroll
  for (int h = 0; h < 12; ++h) {
    F[h] += __shfl_xor(F[h], 16);
    F[h] += __shfl_xor(F[h], 32);
  }
  if (lane < 16 && i < NT_) {
    #pragma unroll
    for (int h = 0; h < 12; ++h)
      F_part[((size_t)(b*H_ + h)*NT_ + i)*12 + ht] = F[h];
  }
}

// -------- MFMA flash attention; V read direct from L2-resident VTimg --------
__global__ __launch_bounds__(256) void attn_mfma_kernel(
    const ushort* __restrict__ Qimg, const ushort* __restrict__ Kimg,
    const ushort* __restrict__ VTimg, const ushort* __restrict__ biasTb,
    const float* __restrict__ F_part, const float* __restrict__ box_b,
    ushort* __restrict__ attnimg)
{
  __shared__ __align__(16) ushort kp_lds[NPAD_*64];   // K image; then P; then O-transpose
  const int bx = blockIdx.x;
  const int bh = bx >> 2, rb = bx & 3;
  const int b = bh / H_, h = bh % H_;
  const int tid = threadIdx.x, lane = tid & 63, wid = tid >> 6;
  const int g = lane >> 4, li = lane & 15;

  const ushort* Kb = Kimg  + (size_t)bh*16384;
  const ushort* Vb = VTimg + (size_t)bh*16384;
  #pragma unroll
  for (int t = 0; t < 8; ++t) {
    const int o = (t*4 + wid) * 512;
    __builtin_amdgcn_global_load_lds(
      (const __attribute__((address_space(1))) unsigned int*)(Kb + o + lane*8),
      (__attribute__((address_space(3))) unsigned int*)(kp_lds + o), 16, 0, 0);
  }

  const int i0 = rb*64 + wid*16;
  const int ig = i0 + li;
  const int iq = (ig < N_) ? ig : (N_-1);
  short8 bq[2];
  {
    const ushort* qp = Qimg + ((size_t)bh*NPAD_ + iq)*64;   // Q pre-scaled
    bq[0] = *(const short8*)(qp + g*8);
    bq[1] = *(const short8*)(qp + 32 + g*8);
  }
  __syncthreads();

  f32x4 sacc[16];
  #pragma unroll
  for (int jt = 0; jt < 16; ++jt) sacc[jt] = (f32x4){0.f,0.f,0.f,0.f};
  #pragma unroll
  for (int jt = 0; jt < 16; ++jt) {
    int jr = jt*16 + li;
    #pragma unroll
    for (int kc = 0; kc < 2; ++kc) {
      short8 af = *(const short8*)(kp_lds + jr*64 + ((kc*32 + g*8) ^ ((jr&7)<<3)));
      sacc[jt] = __builtin_amdgcn_mfma_f32_16x16x32_bf16(af, bq[kc], sacc[jt], 0, 0, 0);
    }
  }
  __syncthreads();   // all waves done reading K; kp_lds becomes P

  float fac = 1.0f;
  if (ig < NT_) {
    const float* fp = F_part + ((size_t)bh*NT_ + ig)*12;
    float4 f0 = *(const float4*)fp;
    float4 f1 = *(const float4*)(fp+4);
    float4 f2 = *(const float4*)(fp+8);
    fac = box_b[h] + f0.x+f0.y+f0.z+f0.w + f1.x+f1.y+f1.z+f1.w + f2.x+f2.y+f2.z+f2.w;
  }
  const ushort* bT = biasTb + (size_t)h*NPAD_*NPAD_;
  float mloc = -1e30f;
  #pragma unroll
  for (int jt = 0; jt < 16; ++jt) {
    #pragma unroll
    for (int r = 0; r < 4; ++r) {
      int j = jt*16 + g*4 + r;
      float sv = sacc[jt][r] + bf2f(bT[(size_t)j*NPAD_ + i0 + li]);
      if (ig < NT_ && j >= NT_) sv *= fac;
      if (j >= N_) sv = -1e30f;
      sacc[jt][r] = sv;
      mloc = fmaxf(mloc, sv);
    }
  }
  mloc = fmaxf(mloc, __shfl_xor(mloc, 16));
  mloc = fmaxf(mloc, __shfl_xor(mloc, 32));
  float ssum = 0.f;
  #pragma unroll
  for (int jt = 0; jt < 16; ++jt) {
    #pragma unroll
    for (int r = 0; r < 4; ++r) {
      float e = __expf(sacc[jt][r] - mloc);
      sacc[jt][r] = e;
      ssum += e;
    }
  }
  ssum += __shfl_xor(ssum, 16);
  ssum += __shfl_xor(ssum, 32);
  const float inv = 1.0f / ssum;

  ushort* pbase = kp_lds + wid*4096 + li*256;
  const int swz = (li & 7) << 3;
  #pragma unroll
  for (int jt = 0; jt < 16; ++jt) {
    unsigned w0 = (unsigned)f2bf(sacc[jt][0]*inv) | ((unsigned)f2bf(sacc[jt][1]*inv) << 16);
    unsigned w1 = (unsigned)f2bf(sacc[jt][2]*inv) | ((unsigned)f2bf(sacc[jt][3]*inv) << 16);
    *(uint2*)(pbase + ((jt*16 + g*4) ^ swz)) = make_uint2(w0, w1);
  }

  f32x4 oacc[4];
  #pragma unroll
  for (int dt = 0; dt < 4; ++dt) oacc[dt] = (f32x4){0.f,0.f,0.f,0.f};
  #pragma unroll
  for (int jc = 0; jc < 8; ++jc) {
    short8 pf = *(const short8*)(pbase + ((jc*32 + g*8) ^ swz));
    #pragma unroll
    for (int dt = 0; dt < 4; ++dt) {
      int row = dt*16 + li;
      short8 vf = *(const short8*)(Vb + row*NPAD_ + ((jc*32 + g*8) ^ ((row&7)<<3)));
      oacc[dt] = __builtin_amdgcn_mfma_f32_16x16x32_bf16(vf, pf, oacc[dt], 0, 0, 0);
    }
  }

  // ---- per-wave LDS transpose in own 8KB region (no barrier needed) ----
  float* tb = (float*)(kp_lds + wid*4096);
  #pragma unroll
  for (int dt = 0; dt < 4; ++dt)
    #pragma unroll
    for (int rr = 0; rr < 4; ++rr)
      tb[(dt*16 + g*4 + rr)*19 + li] = oacc[dt][rr];

  const int rtok = lane >> 2, cg = lane & 3;
  const int tokl = i0 + rtok;
  if (tokl < N_) {
    const int m = b*N_ + tokl;
    const int mbm = m >> 7, rr_ = m & 127, rx = rr_ & 7;
    const int kbb = h*2 + (cg >> 1);
    ushort* baseimg = attnimg + (((size_t)(mbm*KB_ + kbb))*128 + rr_)*64;
    #pragma unroll
    for (int half = 0; half < 2; ++half) {
      us8 hv, lv;
      #pragma unroll
      for (int e = 0; e < 8; ++e) {
        float v = tb[(cg*16 + half*8 + e)*19 + rtok];
        ushort hh, ll; split2(v, hh, ll);
        hv[e] = hh; lv[e] = ll;
      }
      const int c0 = (cg & 1)*2 + half;
      *(us8*)(baseimg + ((c0 ^ rx) * 8))        = hv;
      *(us8*)(baseimg + (((c0 ^ 4) ^ rx) * 8))  = lv;
    }
  }
}

extern "C" void kernel_launch(void* const* d_in, const int* in_sizes, int n_in,
                              void* d_out, int out_size, void* d_ws, size_t ws_size,
                              hipStream_t stream)
{
  const float* x         = (const float*)d_in[0];
  const float* boxmask   = (const float*)d_in[1];
  const float* qkv_w     = (const float*)d_in[2];
  const float* qkv_b     = (const float*)d_in[3];
  const float* proj_w    = (const float*)d_in[4];
  const float* proj_b    = (const float*)d_in[5];
  const float* box_w     = (const float*)d_in[6];
  const float* box_b     = (const float*)d_in[7];
  const float* rpe_table = (const float*)d_in[8];
  const int*   rpe_index = (const int*)d_in[9];
  const int rpe_m = in_sizes[8] / H_;   // 1698

  float* ws      = (float*)d_ws;
  float* G       = ws;                                   // 589,824 f
  float* F_part  = G + (size_t)B_*H_*H_*64;              // 451,584 f
  ushort* biasTb = (ushort*)(F_part + (size_t)B_*H_*NT_*12);  // 786,432 us
  ushort* ximg    = biasTb   + (size_t)H_*NPAD_*NPAD_;
  ushort* wqkvimg  = ximg     + (size_t)MP_*C_*2;        // 24,182,784 us
  ushort* wprojimg = wqkvimg  + (size_t)C3_*C_*2;        // 3,538,944 us
  ushort* Qimg     = wprojimg + (size_t)C_*C_*2;         // 1,179,648 us
  ushort* Kimg     = Qimg     + (size_t)B_*H_*NPAD_*64;  // 12,582,912 us each
  ushort* VTimg    = Kimg     + (size_t)B_*H_*NPAD_*64;
  ushort* attnimg  = ximg;   // alias: x image dead after QKV GEMM
  float* out     = (float*)d_out;

  // 0) merged prep: splits + bf16 biasT + G
  prep_kernel<<<PREP_X_+PREP_WQ_+PREP_WP_+PREP_BT_+PREP_G_, 256, 0, stream>>>(
      x, qkv_w, proj_w, rpe_table, rpe_index, boxmask, box_w,
      ximg, wqkvimg, wprojimg, biasTb, G, rpe_m);
  // 1) QKV projection -> bf16 Q/K/VT images (XCD-swizzled 1D grid)
  gemm3_qkv_kernel<<<NWG_QKV_, 256, 0, stream>>>(wqkvimg, ximg, qkv_b, Qimg, Kimg, VTimg, KB_);
  // 2) template attention (MFMA) -> F_part
  tmpl_kernel<<<B_*H_, 256, 0, stream>>>(Qimg, Kimg, G, biasTb, F_part);
  // 3) MFMA attention -> attn image
  attn_mfma_kernel<<<B_*H_*4, 256, 0, stream>>>(Qimg, Kimg, VTimg, biasTb, F_part, box_b, attnimg);
  // 4) output projection (bf16x3 MFMA, fp32 out, XCD-swizzled)
  gemm3_kernel<<<NWG_PROJ_, 256, 0, stream>>>(attnimg, wprojimg, proj_b, out, KB_, C_, M_);
}